// Round 2
// baseline (710.876 us; speedup 1.0000x reference)
//
#include <hip/hip_runtime.h>
#include <hip/hip_bf16.h>

#define B_   8
#define S_   2048
#define DIN  512
#define DATT 512
#define DROT 256

typedef __attribute__((ext_vector_type(4))) float f32x4;
typedef __attribute__((ext_vector_type(8))) short bf16x8;

__device__ __forceinline__ short f2bf(float f) {
    __hip_bfloat16 h = __float2bfloat16(f);
    return *reinterpret_cast<short*>(&h);
}

// ---- K0: rotary cos/sin tables: [s][j] j=0..255, pairs duplicated ----
__global__ void k_tables(float* __restrict__ cosT, float* __restrict__ sinT) {
    int idx = blockIdx.x * 256 + threadIdx.x;   // 2048*128
    if (idx >= S_ * 128) return;
    int s = idx >> 7;
    int i = idx & 127;
    float e    = (float)(2 * i) / (float)DROT;
    float invf = 1.0f / powf(10000.0f, e);
    float f    = (float)s * invf;
    float c = cosf(f), sn = sinf(f);
    cosT[s * 256 + 2 * i]     = c;
    cosT[s * 256 + 2 * i + 1] = c;
    sinT[s * 256 + 2 * i]     = sn;
    sinT[s * 256 + 2 * i + 1] = sn;
}

// ---- K1: X(16384x512) @ W(512x512) + bias, optional rotary, -> bf16 ----
__global__ __launch_bounds__(256) void k_proj(
    const float* __restrict__ X, const float* __restrict__ W,
    const float* __restrict__ bias, short* __restrict__ Out,
    const float* __restrict__ cosT, const float* __restrict__ sinT, int doRot)
{
    __shared__ short As[128 * 40];   // [row][k], pad 40 (80B stride, 16B aligned)
    __shared__ short Bs[128 * 40];   // [n][k]  (W tile transposed)
    int t = threadIdx.x;
    int l = t & 63, w = t >> 6;
    int wr = (w >> 1) * 64, wc = (w & 1) * 64;
    int fr = l & 15, fk = (l >> 4) * 8;
    int rowBase = blockIdx.y * 128;
    int nBase   = blockIdx.x * 128;

    f32x4 acc[4][4] = {};

    int trA = t >> 3, tcA = (t & 7) * 4;
    int kkB = t >> 5, nnB = (t & 31) * 4;

    for (int k0 = 0; k0 < DIN; k0 += 32) {
        for (int ii = 0; ii < 4; ++ii) {            // A: 128x32 fp32 -> bf16
            int r = trA + 32 * ii;
            float4 v = *(const float4*)&X[(size_t)(rowBase + r) * DIN + k0 + tcA];
            short4 s4 = make_short4(f2bf(v.x), f2bf(v.y), f2bf(v.z), f2bf(v.w));
            *(short4*)&As[r * 40 + tcA] = s4;
        }
        for (int ii = 0; ii < 4; ++ii) {            // B: 32x128 -> transposed
            int kk = kkB + 8 * ii;
            float4 v = *(const float4*)&W[(size_t)(k0 + kk) * DATT + nBase + nnB];
            Bs[(nnB + 0) * 40 + kk] = f2bf(v.x);
            Bs[(nnB + 1) * 40 + kk] = f2bf(v.y);
            Bs[(nnB + 2) * 40 + kk] = f2bf(v.z);
            Bs[(nnB + 3) * 40 + kk] = f2bf(v.w);
        }
        __syncthreads();
        bf16x8 af[4], bfr[4];
        for (int m = 0; m < 4; ++m)
            af[m] = *(const bf16x8*)&As[(wr + m * 16 + fr) * 40 + fk];
        for (int n = 0; n < 4; ++n)
            bfr[n] = *(const bf16x8*)&Bs[(wc + n * 16 + fr) * 40 + fk];
        for (int m = 0; m < 4; ++m)
            for (int n = 0; n < 4; ++n)
                acc[m][n] = __builtin_amdgcn_mfma_f32_16x16x32_bf16(af[m], bfr[n], acc[m][n], 0, 0, 0);
        __syncthreads();
    }

    for (int n = 0; n < 4; ++n) {
        int col = nBase + wc + n * 16 + fr;
        float bc = bias[col];
        for (int m = 0; m < 4; ++m) {
            for (int q = 0; q < 4; ++q) {
                int r = rowBase + wr + m * 16 + (l >> 4) * 4 + q;
                float val = acc[m][n][q] + bc;
                float partner = __shfl_xor(val, 1);   // pair col^1, same row
                float out = val;
                if (doRot && col < DROT) {
                    int s = r & (S_ - 1);
                    float c  = cosT[s * 256 + col];
                    float sn = sinT[s * 256 + col];
                    out = val * c + ((col & 1) ? partner : -partner) * sn;
                }
                Out[(size_t)r * DATT + col] = f2bf(out);
            }
        }
    }
}

// ---- K2: scores = Q @ K^T * scale, mask==0 -> -1e-9, fp32 -> d_out ----
// m97-style staging: global_load_lds width 16 into LINEAR [128][32] tiles.
__global__ __launch_bounds__(256) void k_scores(
    const short* __restrict__ Qb, const short* __restrict__ Kb,
    const int* __restrict__ mask, float* __restrict__ wOut)
{
    __shared__ short As[128 * 32];   // linear, NO padding (global_load_lds dest)
    __shared__ short Bs[128 * 32];
    int t = threadIdx.x;
    int l = t & 63, w = t >> 6;
    int wr = (w >> 1) * 64, wc = (w & 1) * 64;
    int fr = l & 15, fk = (l >> 4) * 8;
    int b = blockIdx.z;
    int iBase = blockIdx.y * 128;
    int jBase = blockIdx.x * 128;
    const short* Qp = Qb + (size_t)b * S_ * DATT;
    const short* Kp = Kb + (size_t)b * S_ * DATT;

    f32x4 acc[4][4] = {};

    // wave w, iter it stages LDS rows [it*64 + w*16, +16); lane l covers
    // row base + (l>>2), shorts (l&3)*8.. — lds slot base+16*l matches exactly.
    int srow = w * 16 + (l >> 2);
    int skol = (l & 3) * 8;

    for (int k0 = 0; k0 < DATT; k0 += 32) {
        for (int it = 0; it < 2; ++it) {
            int r = it * 64 + srow;
            __builtin_amdgcn_global_load_lds(
                (const __attribute__((address_space(1))) void*)
                    &Qp[(size_t)(iBase + r) * DATT + k0 + skol],
                (__attribute__((address_space(3))) void*)
                    &As[(it * 64 + w * 16) * 32],
                16, 0, 0);
            __builtin_amdgcn_global_load_lds(
                (const __attribute__((address_space(1))) void*)
                    &Kp[(size_t)(jBase + r) * DATT + k0 + skol],
                (__attribute__((address_space(3))) void*)
                    &Bs[(it * 64 + w * 16) * 32],
                16, 0, 0);
        }
        __syncthreads();
        bf16x8 af[4], bfr[4];
        for (int m = 0; m < 4; ++m)
            af[m] = *(const bf16x8*)&As[(wr + m * 16 + fr) * 32 + fk];
        for (int n = 0; n < 4; ++n)
            bfr[n] = *(const bf16x8*)&Bs[(wc + n * 16 + fr) * 32 + fk];
        for (int m = 0; m < 4; ++m)
            for (int n = 0; n < 4; ++n)
                acc[m][n] = __builtin_amdgcn_mfma_f32_16x16x32_bf16(af[m], bfr[n], acc[m][n], 0, 0, 0);
        __syncthreads();
    }

    const float scale = 0.04419417382415922f;   // 1/sqrt(512)
    for (int m = 0; m < 4; ++m) {
        for (int q = 0; q < 4; ++q) {
            int i = iBase + wr + m * 16 + (l >> 4) * 4 + q;
            size_t rowOff = ((size_t)b * S_ + i) * S_;
            for (int n = 0; n < 4; ++n) {
                int j = jBase + wc + n * 16 + fr;
                float val = acc[m][n][q] * scale;
                if (mask[rowOff + j] == 0) val = -1e-9f;
                wOut[rowOff + j] = val;
            }
        }
    }
}

// ---- K3: in-place row softmax over 2048 cols ----
__global__ __launch_bounds__(256) void k_softmax(float* __restrict__ wts) {
    size_t row = blockIdx.x;
    float* p = wts + row * S_;
    int t = threadIdx.x, l = t & 63, w = t >> 6;
    float v[8];
    *(float4*)&v[0] = ((const float4*)p)[t];
    *(float4*)&v[4] = ((const float4*)p)[t + 256];
    float mx = v[0];
    for (int j = 1; j < 8; ++j) mx = fmaxf(mx, v[j]);
    for (int off = 32; off; off >>= 1) mx = fmaxf(mx, __shfl_xor(mx, off));
    __shared__ float red[8];
    if (l == 0) red[w] = mx;
    __syncthreads();
    mx = fmaxf(fmaxf(red[0], red[1]), fmaxf(red[2], red[3]));
    float sum = 0.f;
    for (int j = 0; j < 8; ++j) { v[j] = expf(v[j] - mx); sum += v[j]; }
    for (int off = 32; off; off >>= 1) sum += __shfl_xor(sum, off);
    if (l == 0) red[4 + w] = sum;
    __syncthreads();
    sum = red[4] + red[5] + red[6] + red[7];
    float inv = 1.0f / sum;
    for (int j = 0; j < 8; ++j) v[j] *= inv;
    ((float4*)p)[t]       = *(float4*)&v[0];
    ((float4*)p)[t + 256] = *(float4*)&v[4];
}

// ---- K4: context = weights(fp32->bf16) @ V(bf16) ----
__global__ __launch_bounds__(256) void k_context(
    const float* __restrict__ wts, const short* __restrict__ Vb,
    float* __restrict__ ctx)
{
    __shared__ short As[128 * 40];   // [i][j]
    __shared__ short Bs[128 * 40];   // [d][j]  (V tile transposed)
    int t = threadIdx.x;
    int l = t & 63, w = t >> 6;
    int wr = (w >> 1) * 64, wc = (w & 1) * 64;
    int fr = l & 15, fk = (l >> 4) * 8;
    int b = blockIdx.z;
    int iBase = blockIdx.y * 128;
    int nBase = blockIdx.x * 128;
    const float* Wp = wts + (size_t)b * S_ * S_;
    const short* Vp = Vb + (size_t)b * S_ * DATT;

    f32x4 acc[4][4] = {};
    int trA = t >> 3, tcA = (t & 7) * 4;
    int jjB = t >> 5, ddB = (t & 31) * 4;

    for (int k0 = 0; k0 < S_; k0 += 32) {
        for (int ii = 0; ii < 4; ++ii) {            // A: weights fp32 -> bf16
            int r = trA + 32 * ii;
            float4 v = *(const float4*)&Wp[(size_t)(iBase + r) * S_ + k0 + tcA];
            short4 s4 = make_short4(f2bf(v.x), f2bf(v.y), f2bf(v.z), f2bf(v.w));
            *(short4*)&As[r * 40 + tcA] = s4;
        }
        for (int ii = 0; ii < 4; ++ii) {            // B: V 32x128 -> transposed
            int jj = jjB + 8 * ii;
            short4 v = *(const short4*)&Vp[(size_t)(k0 + jj) * DATT + nBase + ddB];
            Bs[(ddB + 0) * 40 + jj] = v.x;
            Bs[(ddB + 1) * 40 + jj] = v.y;
            Bs[(ddB + 2) * 40 + jj] = v.z;
            Bs[(ddB + 3) * 40 + jj] = v.w;
        }
        __syncthreads();
        bf16x8 af[4], bfr[4];
        for (int m = 0; m < 4; ++m)
            af[m] = *(const bf16x8*)&As[(wr + m * 16 + fr) * 40 + fk];
        for (int n = 0; n < 4; ++n)
            bfr[n] = *(const bf16x8*)&Bs[(wc + n * 16 + fr) * 40 + fk];
        for (int m = 0; m < 4; ++m)
            for (int n = 0; n < 4; ++n)
                acc[m][n] = __builtin_amdgcn_mfma_f32_16x16x32_bf16(af[m], bfr[n], acc[m][n], 0, 0, 0);
        __syncthreads();
    }

    for (int m = 0; m < 4; ++m) {
        for (int q = 0; q < 4; ++q) {
            int i = iBase + wr + m * 16 + (l >> 4) * 4 + q;
            for (int n = 0; n < 4; ++n) {
                int d = nBase + wc + n * 16 + fr;
                ctx[((size_t)b * S_ + i) * DATT + d] = acc[m][n][q];
            }
        }
    }
}

extern "C" void kernel_launch(void* const* d_in, const int* in_sizes, int n_in,
                              void* d_out, int out_size, void* d_ws, size_t ws_size,
                              hipStream_t stream) {
    const float* query = (const float*)d_in[0];
    const float* key   = (const float*)d_in[1];
    const float* value = (const float*)d_in[2];
    const int*   mask  = (const int*)d_in[3];
    const float* Wq = (const float*)d_in[4];
    const float* bq = (const float*)d_in[5];
    const float* Wk = (const float*)d_in[6];
    const float* bk = (const float*)d_in[7];
    const float* Wv = (const float*)d_in[8];
    const float* bv = (const float*)d_in[9];

    float* ctx = (float*)d_out;                               // B*S*DATT
    float* wts = ctx + (size_t)B_ * S_ * DATT;                // B*S*S

    const size_t NELEM = (size_t)B_ * S_ * DATT;              // 8.39M
    short* Qb = (short*)d_ws;
    short* Kb = Qb + NELEM;
    short* Vb = Kb + NELEM;
    float* cosT = (float*)(Vb + NELEM);
    float* sinT = cosT + (size_t)S_ * 256;

    k_tables<<<dim3((S_ * 128) / 256), 256, 0, stream>>>(cosT, sinT);
    k_proj<<<dim3(4, 128), 256, 0, stream>>>(query, Wq, bq, Qb, cosT, sinT, 1);
    k_proj<<<dim3(4, 128), 256, 0, stream>>>(key,   Wk, bk, Kb, cosT, sinT, 1);
    k_proj<<<dim3(4, 128), 256, 0, stream>>>(value, Wv, bv, Vb, cosT, sinT, 0);
    k_scores<<<dim3(16, 16, 8), 256, 0, stream>>>(Qb, Kb, mask, wts);
    k_softmax<<<dim3(B_ * S_), 256, 0, stream>>>(wts);
    k_context<<<dim3(4, 16, 8), 256, 0, stream>>>(wts, Vb, ctx);
}

// Round 3
// 596.676 us; speedup vs baseline: 1.1914x; 1.1914x over previous
//
#include <hip/hip_runtime.h>
#include <hip/hip_bf16.h>

#define B_   8
#define S_   2048
#define DIN  512
#define DATT 512
#define DROT 256

typedef __attribute__((ext_vector_type(4))) float f32x4;
typedef __attribute__((ext_vector_type(8))) short bf16x8;

__device__ __forceinline__ short f2bf(float f) {
    __hip_bfloat16 h = __float2bfloat16(f);
    return *reinterpret_cast<short*>(&h);
}

// ---- K0: rotary cos/sin tables ----
__global__ void k_tables(float* __restrict__ cosT, float* __restrict__ sinT) {
    int idx = blockIdx.x * 256 + threadIdx.x;
    if (idx >= S_ * 128) return;
    int s = idx >> 7;
    int i = idx & 127;
    float e    = (float)(2 * i) / (float)DROT;
    float invf = 1.0f / powf(10000.0f, e);
    float f    = (float)s * invf;
    float c = cosf(f), sn = sinf(f);
    cosT[s * 256 + 2 * i]     = c;
    cosT[s * 256 + 2 * i + 1] = c;
    sinT[s * 256 + 2 * i]     = sn;
    sinT[s * 256 + 2 * i + 1] = sn;
}

// ---- K0b: W(512x512 fp32) -> Wt bf16 [n][k], 3 matrices ----
__global__ __launch_bounds__(256) void k_wt(
    const float* __restrict__ Wq, const float* __restrict__ Wk,
    const float* __restrict__ Wv,
    short* __restrict__ WtQ, short* __restrict__ WtK, short* __restrict__ WtV)
{
    const float* W; short* Wt;
    if (blockIdx.y == 0)      { W = Wq; Wt = WtQ; }
    else if (blockIdx.y == 1) { W = Wk; Wt = WtK; }
    else                      { W = Wv; Wt = WtV; }
    int kt = blockIdx.x & 7, nt = blockIdx.x >> 3;
    int k0 = kt * 64, n0 = nt * 64;
    __shared__ float tile[64 * 68];   // stride 68 floats (16B-aligned rows)
    int t = threadIdx.x;
    #pragma unroll
    for (int i = 0; i < 4; ++i) {
        int slot = t + 256 * i;          // 1024 float4 slots
        int row = slot >> 4;             // k-row
        int c4  = (slot & 15) * 4;       // n-col
        float4 v = *(const float4*)&W[(size_t)(k0 + row) * DATT + n0 + c4];
        *(float4*)&tile[row * 68 + c4] = v;
    }
    __syncthreads();
    int nr = t >> 2, kq = (t & 3) * 16;
    bf16x8 o0, o1;
    #pragma unroll
    for (int j = 0; j < 8; ++j) o0[j] = f2bf(tile[(kq + j) * 68 + nr]);
    #pragma unroll
    for (int j = 0; j < 8; ++j) o1[j] = f2bf(tile[(kq + 8 + j) * 68 + nr]);
    *(bf16x8*)&Wt[(size_t)(n0 + nr) * DIN + k0 + kq]     = o0;
    *(bf16x8*)&Wt[(size_t)(n0 + nr) * DIN + k0 + kq + 8] = o1;
}

// ---- K1: X(16384x512 fp32) @ Wt^T + bias, optional rotary -> bf16 row-major ----
// A: reg-staged fp32->bf16 (padded 40); B: global_load_lds from Wt (linear 32)
__global__ __launch_bounds__(256) void k_proj(
    const float* __restrict__ X, const short* __restrict__ Wt,
    const float* __restrict__ bias, short* __restrict__ Out,
    const float* __restrict__ cosT, const float* __restrict__ sinT, int doRot)
{
    __shared__ short As[128 * 40];
    __shared__ short Bs[128 * 32];   // linear: global_load_lds dest
    int t = threadIdx.x;
    int l = t & 63, w = t >> 6;
    int wr = (w >> 1) * 64, wc = (w & 1) * 64;
    int fr = l & 15, fk = (l >> 4) * 8;
    int rowBase = blockIdx.y * 128;
    int nBase   = blockIdx.x * 128;

    f32x4 acc[4][4] = {};
    int trA = t >> 3, tcA = (t & 7) * 4;
    int srow = w * 16 + (l >> 2), skol = (l & 3) * 8;

    for (int k0 = 0; k0 < DIN; k0 += 32) {
        #pragma unroll
        for (int it = 0; it < 2; ++it) {
            int r = it * 64 + srow;
            __builtin_amdgcn_global_load_lds(
                (const __attribute__((address_space(1))) void*)
                    &Wt[(size_t)(nBase + r) * DIN + k0 + skol],
                (__attribute__((address_space(3))) void*)
                    &Bs[(it * 64 + w * 16) * 32],
                16, 0, 0);
        }
        #pragma unroll
        for (int ii = 0; ii < 4; ++ii) {
            int r = trA + 32 * ii;
            float4 v = *(const float4*)&X[(size_t)(rowBase + r) * DIN + k0 + tcA];
            short4 s4 = make_short4(f2bf(v.x), f2bf(v.y), f2bf(v.z), f2bf(v.w));
            *(short4*)&As[r * 40 + tcA] = s4;
        }
        __syncthreads();
        bf16x8 af[4], bfr[4];
        #pragma unroll
        for (int m = 0; m < 4; ++m)
            af[m] = *(const bf16x8*)&As[(wr + m * 16 + fr) * 40 + fk];
        #pragma unroll
        for (int n = 0; n < 4; ++n)
            bfr[n] = *(const bf16x8*)&Bs[(wc + n * 16 + fr) * 32 + fk];
        #pragma unroll
        for (int m = 0; m < 4; ++m)
            #pragma unroll
            for (int n = 0; n < 4; ++n)
                acc[m][n] = __builtin_amdgcn_mfma_f32_16x16x32_bf16(af[m], bfr[n], acc[m][n], 0, 0, 0);
        __syncthreads();
    }

    for (int n = 0; n < 4; ++n) {
        int col = nBase + wc + n * 16 + fr;
        float bc = bias[col];
        for (int m = 0; m < 4; ++m) {
            for (int q = 0; q < 4; ++q) {
                int r = rowBase + wr + m * 16 + (l >> 4) * 4 + q;
                float val = acc[m][n][q] + bc;
                float partner = __shfl_xor(val, 1);   // pair col^1, same row
                float out = val;
                if (doRot && col < DROT) {
                    int s = r & (S_ - 1);
                    float c  = cosT[s * 256 + col];
                    float sn = sinT[s * 256 + col];
                    out = val * c + ((col & 1) ? partner : -partner) * sn;
                }
                Out[(size_t)r * DATT + col] = f2bf(out);
            }
        }
    }
}

// ---- K1b: Vb[2048][512] -> Vt[512][2048] bf16, per batch ----
__global__ __launch_bounds__(256) void k_vt(
    const short* __restrict__ Vb, short* __restrict__ Vt)
{
    int b = blockIdx.z;
    int d0 = blockIdx.x * 64;   // 8 tiles
    int r0 = blockIdx.y * 64;   // 32 tiles
    const short* Vp = Vb + (size_t)b * S_ * DATT;
    short* Tp = Vt + (size_t)b * DATT * S_;
    __shared__ short tile[64 * 66];   // [r][d], stride 66 (+2 pad)
    int t = threadIdx.x;
    #pragma unroll
    for (int i = 0; i < 2; ++i) {
        int slot = t + 256 * i;        // 512 short8 slots
        int row = slot >> 3;           // r-row
        int c8  = (slot & 7) * 8;      // d-col
        bf16x8 v = *(const bf16x8*)&Vp[(size_t)(r0 + row) * DATT + d0 + c8];
        #pragma unroll
        for (int j = 0; j < 8; ++j) tile[row * 66 + c8 + j] = v[j];
    }
    __syncthreads();
    int dr = t >> 2, rq = (t & 3) * 16;
    bf16x8 o0, o1;
    #pragma unroll
    for (int j = 0; j < 8; ++j) o0[j] = tile[(rq + j) * 66 + dr];
    #pragma unroll
    for (int j = 0; j < 8; ++j) o1[j] = tile[(rq + 8 + j) * 66 + dr];
    *(bf16x8*)&Tp[(size_t)(d0 + dr) * S_ + r0 + rq]     = o0;
    *(bf16x8*)&Tp[(size_t)(d0 + dr) * S_ + r0 + rq + 8] = o1;
}

// ---- K2: scores = Q @ K^T * scale, mask==0 -> -1e-9, fp32 -> d_out ----
__global__ __launch_bounds__(256) void k_scores(
    const short* __restrict__ Qb, const short* __restrict__ Kb,
    const int* __restrict__ mask, float* __restrict__ wOut)
{
    __shared__ short As[128 * 32];
    __shared__ short Bs[128 * 32];
    int t = threadIdx.x;
    int l = t & 63, w = t >> 6;
    int wr = (w >> 1) * 64, wc = (w & 1) * 64;
    int fr = l & 15, fk = (l >> 4) * 8;
    int b = blockIdx.z;
    int iBase = blockIdx.y * 128;
    int jBase = blockIdx.x * 128;
    const short* Qp = Qb + (size_t)b * S_ * DATT;
    const short* Kp = Kb + (size_t)b * S_ * DATT;

    f32x4 acc[4][4] = {};
    int srow = w * 16 + (l >> 2);
    int skol = (l & 3) * 8;

    for (int k0 = 0; k0 < DATT; k0 += 32) {
        #pragma unroll
        for (int it = 0; it < 2; ++it) {
            int r = it * 64 + srow;
            __builtin_amdgcn_global_load_lds(
                (const __attribute__((address_space(1))) void*)
                    &Qp[(size_t)(iBase + r) * DATT + k0 + skol],
                (__attribute__((address_space(3))) void*)
                    &As[(it * 64 + w * 16) * 32],
                16, 0, 0);
            __builtin_amdgcn_global_load_lds(
                (const __attribute__((address_space(1))) void*)
                    &Kp[(size_t)(jBase + r) * DATT + k0 + skol],
                (__attribute__((address_space(3))) void*)
                    &Bs[(it * 64 + w * 16) * 32],
                16, 0, 0);
        }
        __syncthreads();
        bf16x8 af[4], bfr[4];
        #pragma unroll
        for (int m = 0; m < 4; ++m)
            af[m] = *(const bf16x8*)&As[(wr + m * 16 + fr) * 32 + fk];
        #pragma unroll
        for (int n = 0; n < 4; ++n)
            bfr[n] = *(const bf16x8*)&Bs[(wc + n * 16 + fr) * 32 + fk];
        #pragma unroll
        for (int m = 0; m < 4; ++m)
            #pragma unroll
            for (int n = 0; n < 4; ++n)
                acc[m][n] = __builtin_amdgcn_mfma_f32_16x16x32_bf16(af[m], bfr[n], acc[m][n], 0, 0, 0);
        __syncthreads();
    }

    const float scale = 0.04419417382415922f;   // 1/sqrt(512)
    for (int m = 0; m < 4; ++m) {
        for (int q = 0; q < 4; ++q) {
            int i = iBase + wr + m * 16 + (l >> 4) * 4 + q;
            size_t rowOff = ((size_t)b * S_ + i) * S_;
            for (int n = 0; n < 4; ++n) {
                int j = jBase + wc + n * 16 + fr;
                float val = acc[m][n][q] * scale;
                if (mask[rowOff + j] == 0) val = -1e-9f;
                wOut[rowOff + j] = val;
            }
        }
    }
}

// ---- K3: in-place row softmax; optionally emits bf16 copy Pb ----
__global__ __launch_bounds__(256) void k_softmax(
    float* __restrict__ wts, short* __restrict__ Pb, int pbe)
{
    size_t row = blockIdx.x;
    float* p = wts + row * S_;
    int t = threadIdx.x, l = t & 63, w = t >> 6;
    float v[8];
    *(float4*)&v[0] = ((const float4*)p)[t];
    *(float4*)&v[4] = ((const float4*)p)[t + 256];
    float mx = v[0];
    #pragma unroll
    for (int j = 1; j < 8; ++j) mx = fmaxf(mx, v[j]);
    for (int off = 32; off; off >>= 1) mx = fmaxf(mx, __shfl_xor(mx, off));
    __shared__ float red[8];
    if (l == 0) red[w] = mx;
    __syncthreads();
    mx = fmaxf(fmaxf(red[0], red[1]), fmaxf(red[2], red[3]));
    float sum = 0.f;
    #pragma unroll
    for (int j = 0; j < 8; ++j) { v[j] = expf(v[j] - mx); sum += v[j]; }
    for (int off = 32; off; off >>= 1) sum += __shfl_xor(sum, off);
    if (l == 0) red[4 + w] = sum;
    __syncthreads();
    sum = red[4] + red[5] + red[6] + red[7];
    float inv = 1.0f / sum;
    #pragma unroll
    for (int j = 0; j < 8; ++j) v[j] *= inv;
    ((float4*)p)[t]       = *(float4*)&v[0];
    ((float4*)p)[t + 256] = *(float4*)&v[4];
    if (pbe) {
        short* pb = Pb + row * S_;
        *(short4*)&pb[4 * t] = make_short4(f2bf(v[0]), f2bf(v[1]), f2bf(v[2]), f2bf(v[3]));
        *(short4*)&pb[1024 + 4 * t] = make_short4(f2bf(v[4]), f2bf(v[5]), f2bf(v[6]), f2bf(v[7]));
    }
}

// ---- K4a: context = Pb(bf16) @ Vt^T — pure m97 structure ----
__global__ __launch_bounds__(256) void k_ctx_bf16(
    const short* __restrict__ Pb, const short* __restrict__ Vt,
    float* __restrict__ ctx)
{
    __shared__ short As[128 * 32];
    __shared__ short Bs[128 * 32];
    int t = threadIdx.x;
    int l = t & 63, w = t >> 6;
    int wr = (w >> 1) * 64, wc = (w & 1) * 64;
    int fr = l & 15, fk = (l >> 4) * 8;
    int b = blockIdx.z;
    int iBase = blockIdx.y * 128;
    int nBase = blockIdx.x * 128;
    const short* Ap = Pb + (size_t)b * S_ * S_;
    const short* Bp = Vt + (size_t)b * DATT * S_;

    f32x4 acc[4][4] = {};
    int srow = w * 16 + (l >> 2);
    int skol = (l & 3) * 8;

    for (int k0 = 0; k0 < S_; k0 += 32) {
        #pragma unroll
        for (int it = 0; it < 2; ++it) {
            int r = it * 64 + srow;
            __builtin_amdgcn_global_load_lds(
                (const __attribute__((address_space(1))) void*)
                    &Ap[(size_t)(iBase + r) * S_ + k0 + skol],
                (__attribute__((address_space(3))) void*)
                    &As[(it * 64 + w * 16) * 32],
                16, 0, 0);
            __builtin_amdgcn_global_load_lds(
                (const __attribute__((address_space(1))) void*)
                    &Bp[(size_t)(nBase + r) * S_ + k0 + skol],
                (__attribute__((address_space(3))) void*)
                    &Bs[(it * 64 + w * 16) * 32],
                16, 0, 0);
        }
        __syncthreads();
        bf16x8 af[4], bfr[4];
        #pragma unroll
        for (int m = 0; m < 4; ++m)
            af[m] = *(const bf16x8*)&As[(wr + m * 16 + fr) * 32 + fk];
        #pragma unroll
        for (int n = 0; n < 4; ++n)
            bfr[n] = *(const bf16x8*)&Bs[(wc + n * 16 + fr) * 32 + fk];
        #pragma unroll
        for (int m = 0; m < 4; ++m)
            #pragma unroll
            for (int n = 0; n < 4; ++n)
                acc[m][n] = __builtin_amdgcn_mfma_f32_16x16x32_bf16(af[m], bfr[n], acc[m][n], 0, 0, 0);
        __syncthreads();
    }

    for (int m = 0; m < 4; ++m) {
        for (int q = 0; q < 4; ++q) {
            int i = iBase + wr + m * 16 + (l >> 4) * 4 + q;
            for (int n = 0; n < 4; ++n) {
                int d = nBase + wc + n * 16 + fr;
                ctx[((size_t)b * S_ + i) * DATT + d] = acc[m][n][q];
            }
        }
    }
}

// ---- K4b: context from fp32 weights (ws-constrained fallback) ----
__global__ __launch_bounds__(256) void k_ctx_f32(
    const float* __restrict__ wts, const short* __restrict__ Vt,
    float* __restrict__ ctx)
{
    __shared__ short As[128 * 40];   // padded (reg-staged conversion)
    __shared__ short Bs[128 * 32];   // linear (global_load_lds)
    int t = threadIdx.x;
    int l = t & 63, w = t >> 6;
    int wr = (w >> 1) * 64, wc = (w & 1) * 64;
    int fr = l & 15, fk = (l >> 4) * 8;
    int b = blockIdx.z;
    int iBase = blockIdx.y * 128;
    int nBase = blockIdx.x * 128;
    const float* Wp = wts + (size_t)b * S_ * S_;
    const short* Bp = Vt + (size_t)b * DATT * S_;

    f32x4 acc[4][4] = {};
    int trA = t >> 3, tcA = (t & 7) * 4;
    int srow = w * 16 + (l >> 2), skol = (l & 3) * 8;

    for (int k0 = 0; k0 < S_; k0 += 32) {
        #pragma unroll
        for (int it = 0; it < 2; ++it) {
            int r = it * 64 + srow;
            __builtin_amdgcn_global_load_lds(
                (const __attribute__((address_space(1))) void*)
                    &Bp[(size_t)(nBase + r) * S_ + k0 + skol],
                (__attribute__((address_space(3))) void*)
                    &Bs[(it * 64 + w * 16) * 32],
                16, 0, 0);
        }
        #pragma unroll
        for (int ii = 0; ii < 4; ++ii) {
            int r = trA + 32 * ii;
            float4 v = *(const float4*)&Wp[(size_t)(iBase + r) * S_ + k0 + tcA];
            short4 s4 = make_short4(f2bf(v.x), f2bf(v.y), f2bf(v.z), f2bf(v.w));
            *(short4*)&As[r * 40 + tcA] = s4;
        }
        __syncthreads();
        bf16x8 af[4], bfr[4];
        #pragma unroll
        for (int m = 0; m < 4; ++m)
            af[m] = *(const bf16x8*)&As[(wr + m * 16 + fr) * 40 + fk];
        #pragma unroll
        for (int n = 0; n < 4; ++n)
            bfr[n] = *(const bf16x8*)&Bs[(wc + n * 16 + fr) * 32 + fk];
        #pragma unroll
        for (int m = 0; m < 4; ++m)
            #pragma unroll
            for (int n = 0; n < 4; ++n)
                acc[m][n] = __builtin_amdgcn_mfma_f32_16x16x32_bf16(af[m], bfr[n], acc[m][n], 0, 0, 0);
        __syncthreads();
    }

    for (int m = 0; m < 4; ++m) {
        for (int q = 0; q < 4; ++q) {
            int i = iBase + wr + m * 16 + (l >> 4) * 4 + q;
            for (int n = 0; n < 4; ++n) {
                int d = nBase + wc + n * 16 + fr;
                ctx[((size_t)b * S_ + i) * DATT + d] = acc[m][n][q];
            }
        }
    }
}

extern "C" void kernel_launch(void* const* d_in, const int* in_sizes, int n_in,
                              void* d_out, int out_size, void* d_ws, size_t ws_size,
                              hipStream_t stream) {
    const float* query = (const float*)d_in[0];
    const float* key   = (const float*)d_in[1];
    const float* value = (const float*)d_in[2];
    const int*   mask  = (const int*)d_in[3];
    const float* Wq = (const float*)d_in[4];
    const float* bq = (const float*)d_in[5];
    const float* Wk = (const float*)d_in[6];
    const float* bk = (const float*)d_in[7];
    const float* Wv = (const float*)d_in[8];
    const float* bv = (const float*)d_in[9];

    float* ctx = (float*)d_out;                    // B*S*DATT fp32
    float* wts = ctx + (size_t)B_ * S_ * DATT;     // B*S*S fp32

    // ws layout (bytes)
    char* ws = (char*)d_ws;
    const size_t SZ_QKV = (size_t)B_ * S_ * DATT * 2;      // 16.78 MB
    const size_t SZ_WT  = (size_t)DATT * DIN * 2;          // 512 KB
    const size_t SZ_TAB = (size_t)S_ * 256 * 4;            // 2 MB
    short* Qb   = (short*)(ws);
    short* Kb   = (short*)(ws + SZ_QKV);
    short* Vt   = (short*)(ws + 2 * SZ_QKV);
    short* WtQ  = (short*)(ws + 3 * SZ_QKV);
    short* WtK  = (short*)(ws + 3 * SZ_QKV + SZ_WT);
    short* WtV  = (short*)(ws + 3 * SZ_QKV + 2 * SZ_WT);
    float* cosT = (float*)(ws + 3 * SZ_QKV + 3 * SZ_WT);
    float* sinT = (float*)(ws + 3 * SZ_QKV + 3 * SZ_WT + SZ_TAB);
    char*  big  = ws + 3 * SZ_QKV + 3 * SZ_WT + 2 * SZ_TAB;
    short* Vb   = (short*)big;                              // dead after k_vt
    short* Pb   = (short*)big;                              // written after k_vt
    const size_t needA = 3 * SZ_QKV + 3 * SZ_WT + 2 * SZ_TAB
                       + (size_t)B_ * S_ * S_ * 2;          // ~123.2 MB
    int usePb = ws_size >= needA ? 1 : 0;

    k_tables<<<dim3((S_ * 128) / 256), 256, 0, stream>>>(cosT, sinT);
    k_wt<<<dim3(64, 3), 256, 0, stream>>>(Wq, Wk, Wv, WtQ, WtK, WtV);
    k_proj<<<dim3(4, 128), 256, 0, stream>>>(query, WtQ, bq, Qb, cosT, sinT, 1);
    k_proj<<<dim3(4, 128), 256, 0, stream>>>(key,   WtK, bk, Kb, cosT, sinT, 1);
    k_proj<<<dim3(4, 128), 256, 0, stream>>>(value, WtV, bv, Vb, cosT, sinT, 0);
    k_vt<<<dim3(8, 32, 8), 256, 0, stream>>>(Vb, Vt);
    k_scores<<<dim3(16, 16, 8), 256, 0, stream>>>(Qb, Kb, mask, wts);
    k_softmax<<<dim3(B_ * S_), 256, 0, stream>>>(wts, Pb, usePb);
    if (usePb)
        k_ctx_bf16<<<dim3(4, 16, 8), 256, 0, stream>>>(Pb, Vt, ctx);
    else
        k_ctx_f32<<<dim3(4, 16, 8), 256, 0, stream>>>(wts, Vt, ctx);
}

// Round 5
// 593.313 us; speedup vs baseline: 1.1981x; 1.0057x over previous
//
#include <hip/hip_runtime.h>
#include <hip/hip_bf16.h>

#define B_   8
#define S_   2048
#define DIN  512
#define DATT 512
#define DROT 256

typedef __attribute__((ext_vector_type(4))) float f32x4;
typedef __attribute__((ext_vector_type(8))) short bf16x8;

__device__ __forceinline__ short f2bf(float f) {
    __hip_bfloat16 h = __float2bfloat16(f);
    return *reinterpret_cast<short*>(&h);
}

// ---- K0: rotary cos/sin tables ----
__global__ void k_tables(float* __restrict__ cosT, float* __restrict__ sinT) {
    int idx = blockIdx.x * 256 + threadIdx.x;
    if (idx >= S_ * 128) return;
    int s = idx >> 7;
    int i = idx & 127;
    float e    = (float)(2 * i) / (float)DROT;
    float invf = 1.0f / powf(10000.0f, e);
    float f    = (float)s * invf;
    float c = cosf(f), sn = sinf(f);
    cosT[s * 256 + 2 * i]     = c;
    cosT[s * 256 + 2 * i + 1] = c;
    sinT[s * 256 + 2 * i]     = sn;
    sinT[s * 256 + 2 * i + 1] = sn;
}

// ---- K0b: W(512x512 fp32) -> Wt bf16 [n][k], 3 matrices ----
__global__ __launch_bounds__(256) void k_wt(
    const float* __restrict__ Wq, const float* __restrict__ Wk,
    const float* __restrict__ Wv,
    short* __restrict__ WtQ, short* __restrict__ WtK, short* __restrict__ WtV)
{
    const float* W; short* Wt;
    if (blockIdx.y == 0)      { W = Wq; Wt = WtQ; }
    else if (blockIdx.y == 1) { W = Wk; Wt = WtK; }
    else                      { W = Wv; Wt = WtV; }
    int kt = blockIdx.x & 7, nt = blockIdx.x >> 3;
    int k0 = kt * 64, n0 = nt * 64;
    __shared__ float tile[64 * 68];
    int t = threadIdx.x;
    #pragma unroll
    for (int i = 0; i < 4; ++i) {
        int slot = t + 256 * i;
        int row = slot >> 4;
        int c4  = (slot & 15) * 4;
        float4 v = *(const float4*)&W[(size_t)(k0 + row) * DATT + n0 + c4];
        *(float4*)&tile[row * 68 + c4] = v;
    }
    __syncthreads();
    int nr = t >> 2, kq = (t & 3) * 16;
    bf16x8 o0, o1;
    #pragma unroll
    for (int j = 0; j < 8; ++j) o0[j] = f2bf(tile[(kq + j) * 68 + nr]);
    #pragma unroll
    for (int j = 0; j < 8; ++j) o1[j] = f2bf(tile[(kq + 8 + j) * 68 + nr]);
    *(bf16x8*)&Wt[(size_t)(n0 + nr) * DIN + k0 + kq]     = o0;
    *(bf16x8*)&Wt[(size_t)(n0 + nr) * DIN + k0 + kq + 8] = o1;
}

// ---- K1: X @ Wt^T + bias, optional rotary -> bf16; LDS-transpose epilogue ----
__global__ __launch_bounds__(256) void k_proj(
    const float* __restrict__ X, const short* __restrict__ Wt,
    const float* __restrict__ bias, short* __restrict__ Out,
    const float* __restrict__ cosT, const float* __restrict__ sinT, int doRot)
{
    __shared__ __align__(16) float smem[4608];     // 18432 B
    short* As = (short*)smem;                      // 128*40 shorts = 10240 B
    short* Bs = (short*)(smem + 2560);             // 128*32 shorts = 8192 B
    float* Ct = smem;                              // 128*34 floats = 17408 B
    int t = threadIdx.x;
    int l = t & 63, w = t >> 6;
    int wr = (w >> 1) * 64, wc = (w & 1) * 64;
    int fr = l & 15, fk = (l >> 4) * 8;
    int rowBase = blockIdx.y * 128;
    int nBase   = blockIdx.x * 128;

    f32x4 acc[4][4] = {};
    int trA = t >> 3, tcA = (t & 7) * 4;
    int srow = w * 16 + (l >> 2), skol = (l & 3) * 8;

    for (int k0 = 0; k0 < DIN; k0 += 32) {
        #pragma unroll
        for (int it = 0; it < 2; ++it) {
            int r = it * 64 + srow;
            __builtin_amdgcn_global_load_lds(
                (const __attribute__((address_space(1))) void*)
                    &Wt[(size_t)(nBase + r) * DIN + k0 + skol],
                (__attribute__((address_space(3))) void*)
                    &Bs[(it * 64 + w * 16) * 32],
                16, 0, 0);
        }
        #pragma unroll
        for (int ii = 0; ii < 4; ++ii) {
            int r = trA + 32 * ii;
            float4 v = *(const float4*)&X[(size_t)(rowBase + r) * DIN + k0 + tcA];
            short4 s4 = make_short4(f2bf(v.x), f2bf(v.y), f2bf(v.z), f2bf(v.w));
            *(short4*)&As[r * 40 + tcA] = s4;
        }
        __syncthreads();
        bf16x8 af[4], bfr[4];
        #pragma unroll
        for (int m = 0; m < 4; ++m)
            af[m] = *(const bf16x8*)&As[(wr + m * 16 + fr) * 40 + fk];
        #pragma unroll
        for (int n = 0; n < 4; ++n)
            bfr[n] = *(const bf16x8*)&Bs[(wc + n * 16 + fr) * 32 + fk];
        #pragma unroll
        for (int m = 0; m < 4; ++m)
            #pragma unroll
            for (int n = 0; n < 4; ++n)
                acc[m][n] = __builtin_amdgcn_mfma_f32_16x16x32_bf16(af[m], bfr[n], acc[m][n], 0, 0, 0);
        __syncthreads();
    }

    // epilogue: 4 chunks of 32 cols via LDS transpose
    for (int ch = 0; ch < 4; ++ch) {
        if ((w & 1) == (ch >> 1)) {
            int nb = (ch & 1) * 2;
            #pragma unroll
            for (int n2 = 0; n2 < 2; ++n2)
                #pragma unroll
                for (int m = 0; m < 4; ++m)
                    #pragma unroll
                    for (int q = 0; q < 4; ++q)
                        Ct[(wr + m * 16 + (l >> 4) * 4 + q) * 34 + n2 * 16 + fr]
                            = acc[m][nb + n2][q];
        }
        __syncthreads();
        {
            int r = t >> 1, seg = (t & 1) * 16;
            int rg = rowBase + r;
            int cg = nBase + ch * 32 + seg;
            float vv[16];
            #pragma unroll
            for (int u = 0; u < 4; ++u)
                *(float4*)&vv[4 * u] = *(float4*)&Ct[r * 34 + seg + 4 * u];
            #pragma unroll
            for (int u = 0; u < 4; ++u) {
                float4 bb = *(const float4*)&bias[cg + 4 * u];
                vv[4 * u + 0] += bb.x; vv[4 * u + 1] += bb.y;
                vv[4 * u + 2] += bb.z; vv[4 * u + 3] += bb.w;
            }
            if (doRot && cg < DROT) {
                int s = rg & (S_ - 1);
                float cs[16], sn[16];
                #pragma unroll
                for (int u = 0; u < 4; ++u) {
                    *(float4*)&cs[4 * u] = *(const float4*)&cosT[s * 256 + cg + 4 * u];
                    *(float4*)&sn[4 * u] = *(const float4*)&sinT[s * 256 + cg + 4 * u];
                }
                #pragma unroll
                for (int j = 0; j < 16; j += 2) {
                    float x1 = vv[j], x2 = vv[j + 1];
                    vv[j]     = x1 * cs[j]     - x2 * sn[j];
                    vv[j + 1] = x2 * cs[j + 1] + x1 * sn[j + 1];
                }
            }
            bf16x8 o0, o1;
            #pragma unroll
            for (int j = 0; j < 8; ++j) { o0[j] = f2bf(vv[j]); o1[j] = f2bf(vv[8 + j]); }
            *(bf16x8*)&Out[(size_t)rg * DATT + cg]     = o0;
            *(bf16x8*)&Out[(size_t)rg * DATT + cg + 8] = o1;
        }
        __syncthreads();
    }
}

// ---- K1b: Vb[2048][512] -> Vt[512][2048] bf16, per batch ----
__global__ __launch_bounds__(256) void k_vt(
    const short* __restrict__ Vb, short* __restrict__ Vt)
{
    int b = blockIdx.z;
    int d0 = blockIdx.x * 64;
    int r0 = blockIdx.y * 64;
    const short* Vp = Vb + (size_t)b * S_ * DATT;
    short* Tp = Vt + (size_t)b * DATT * S_;
    __shared__ short tile[64 * 66];
    int t = threadIdx.x;
    #pragma unroll
    for (int i = 0; i < 2; ++i) {
        int slot = t + 256 * i;
        int row = slot >> 3;
        int c8  = (slot & 7) * 8;
        bf16x8 v = *(const bf16x8*)&Vp[(size_t)(r0 + row) * DATT + d0 + c8];
        #pragma unroll
        for (int j = 0; j < 8; ++j) tile[row * 66 + c8 + j] = v[j];
    }
    __syncthreads();
    int dr = t >> 2, rq = (t & 3) * 16;
    bf16x8 o0, o1;
    #pragma unroll
    for (int j = 0; j < 8; ++j) o0[j] = tile[(rq + j) * 66 + dr];
    #pragma unroll
    for (int j = 0; j < 8; ++j) o1[j] = tile[(rq + 8 + j) * 66 + dr];
    *(bf16x8*)&Tp[(size_t)(d0 + dr) * S_ + r0 + rq]     = o0;
    *(bf16x8*)&Tp[(size_t)(d0 + dr) * S_ + r0 + rq + 8] = o1;
}

// ---- K2: scores = Q @ K^T * scale, mask fused in vectorized readback ----
__global__ __launch_bounds__(256) void k_scores(
    const short* __restrict__ Qb, const short* __restrict__ Kb,
    const int* __restrict__ mask, float* __restrict__ wOut)
{
    __shared__ __align__(16) float smem[4352];     // 17408 B
    short* As = (short*)smem;                      // 8192 B
    short* Bs = (short*)(smem + 2048);             // 8192 B
    float* Ct = smem;                              // 128*34 floats
    int t = threadIdx.x;
    int l = t & 63, w = t >> 6;
    int wr = (w >> 1) * 64, wc = (w & 1) * 64;
    int fr = l & 15, fk = (l >> 4) * 8;
    int b = blockIdx.z;
    int iBase = blockIdx.y * 128;
    int jBase = blockIdx.x * 128;
    const short* Qp = Qb + (size_t)b * S_ * DATT;
    const short* Kp = Kb + (size_t)b * S_ * DATT;

    f32x4 acc[4][4] = {};
    int srow = w * 16 + (l >> 2);
    int skol = (l & 3) * 8;

    for (int k0 = 0; k0 < DATT; k0 += 32) {
        #pragma unroll
        for (int it = 0; it < 2; ++it) {
            int r = it * 64 + srow;
            __builtin_amdgcn_global_load_lds(
                (const __attribute__((address_space(1))) void*)
                    &Qp[(size_t)(iBase + r) * DATT + k0 + skol],
                (__attribute__((address_space(3))) void*)
                    &As[(it * 64 + w * 16) * 32],
                16, 0, 0);
            __builtin_amdgcn_global_load_lds(
                (const __attribute__((address_space(1))) void*)
                    &Kp[(size_t)(jBase + r) * DATT + k0 + skol],
                (__attribute__((address_space(3))) void*)
                    &Bs[(it * 64 + w * 16) * 32],
                16, 0, 0);
        }
        __syncthreads();
        bf16x8 af[4], bfr[4];
        #pragma unroll
        for (int m = 0; m < 4; ++m)
            af[m] = *(const bf16x8*)&As[(wr + m * 16 + fr) * 32 + fk];
        #pragma unroll
        for (int n = 0; n < 4; ++n)
            bfr[n] = *(const bf16x8*)&Bs[(wc + n * 16 + fr) * 32 + fk];
        #pragma unroll
        for (int m = 0; m < 4; ++m)
            #pragma unroll
            for (int n = 0; n < 4; ++n)
                acc[m][n] = __builtin_amdgcn_mfma_f32_16x16x32_bf16(af[m], bfr[n], acc[m][n], 0, 0, 0);
        __syncthreads();
    }

    const float scale = 0.04419417382415922f;   // 1/sqrt(512)
    for (int ch = 0; ch < 4; ++ch) {
        if ((w & 1) == (ch >> 1)) {
            int nb = (ch & 1) * 2;
            #pragma unroll
            for (int n2 = 0; n2 < 2; ++n2)
                #pragma unroll
                for (int m = 0; m < 4; ++m)
                    #pragma unroll
                    for (int q = 0; q < 4; ++q)
                        Ct[(wr + m * 16 + (l >> 4) * 4 + q) * 34 + n2 * 16 + fr]
                            = acc[m][nb + n2][q] * scale;
        }
        __syncthreads();
        {
            int r = t >> 1, seg = (t & 1) * 16;
            int gi = iBase + r;
            size_t base = ((size_t)b * S_ + gi) * S_ + jBase + ch * 32 + seg;
            #pragma unroll
            for (int u = 0; u < 4; ++u) {
                float4 vv = *(float4*)&Ct[r * 34 + seg + 4 * u];
                int4  mm = *(const int4*)&mask[base + 4 * u];
                vv.x = (mm.x == 0) ? -1e-9f : vv.x;
                vv.y = (mm.y == 0) ? -1e-9f : vv.y;
                vv.z = (mm.z == 0) ? -1e-9f : vv.z;
                vv.w = (mm.w == 0) ? -1e-9f : vv.w;
                *(float4*)&wOut[base + 4 * u] = vv;
            }
        }
        __syncthreads();
    }
}

// ---- K3: in-place row softmax; emits bf16 copy Pb ----
__global__ __launch_bounds__(256) void k_softmax(
    float* __restrict__ wts, short* __restrict__ Pb, int pbe)
{
    size_t row = blockIdx.x;
    float* p = wts + row * S_;
    int t = threadIdx.x, l = t & 63, w = t >> 6;
    float v[8];
    *(float4*)&v[0] = ((const float4*)p)[t];
    *(float4*)&v[4] = ((const float4*)p)[t + 256];
    float mx = v[0];
    #pragma unroll
    for (int j = 1; j < 8; ++j) mx = fmaxf(mx, v[j]);
    for (int off = 32; off; off >>= 1) mx = fmaxf(mx, __shfl_xor(mx, off));
    __shared__ float red[8];
    if (l == 0) red[w] = mx;
    __syncthreads();
    mx = fmaxf(fmaxf(red[0], red[1]), fmaxf(red[2], red[3]));
    float sum = 0.f;
    #pragma unroll
    for (int j = 0; j < 8; ++j) { v[j] = expf(v[j] - mx); sum += v[j]; }
    for (int off = 32; off; off >>= 1) sum += __shfl_xor(sum, off);
    if (l == 0) red[4 + w] = sum;
    __syncthreads();
    sum = red[4] + red[5] + red[6] + red[7];
    float inv = 1.0f / sum;
    #pragma unroll
    for (int j = 0; j < 8; ++j) v[j] *= inv;
    ((float4*)p)[t]       = *(float4*)&v[0];
    ((float4*)p)[t + 256] = *(float4*)&v[4];
    if (pbe) {
        short* pb = Pb + row * S_;
        *(short4*)&pb[4 * t] = make_short4(f2bf(v[0]), f2bf(v[1]), f2bf(v[2]), f2bf(v[3]));
        *(short4*)&pb[1024 + 4 * t] = make_short4(f2bf(v[4]), f2bf(v[5]), f2bf(v[6]), f2bf(v[7]));
    }
}

// ---- K4a: context = Pb(bf16) @ Vt^T; LDS-transpose epilogue ----
__global__ __launch_bounds__(256) void k_ctx_bf16(
    const short* __restrict__ Pb, const short* __restrict__ Vt,
    float* __restrict__ ctx)
{
    __shared__ __align__(16) float smem[4352];
    short* As = (short*)smem;
    short* Bs = (short*)(smem + 2048);
    float* Ct = smem;
    int t = threadIdx.x;
    int l = t & 63, w = t >> 6;
    int wr = (w >> 1) * 64, wc = (w & 1) * 64;
    int fr = l & 15, fk = (l >> 4) * 8;
    int b = blockIdx.z;
    int iBase = blockIdx.y * 128;
    int nBase = blockIdx.x * 128;
    const short* Ap = Pb + (size_t)b * S_ * S_;
    const short* Bp = Vt + (size_t)b * DATT * S_;

    f32x4 acc[4][4] = {};
    int srow = w * 16 + (l >> 2);
    int skol = (l & 3) * 8;

    for (int k0 = 0; k0 < S_; k0 += 32) {
        #pragma unroll
        for (int it = 0; it < 2; ++it) {
            int r = it * 64 + srow;
            __builtin_amdgcn_global_load_lds(
                (const __attribute__((address_space(1))) void*)
                    &Ap[(size_t)(iBase + r) * S_ + k0 + skol],
                (__attribute__((address_space(3))) void*)
                    &As[(it * 64 + w * 16) * 32],
                16, 0, 0);
            __builtin_amdgcn_global_load_lds(
                (const __attribute__((address_space(1))) void*)
                    &Bp[(size_t)(nBase + r) * S_ + k0 + skol],
                (__attribute__((address_space(3))) void*)
                    &Bs[(it * 64 + w * 16) * 32],
                16, 0, 0);
        }
        __syncthreads();
        bf16x8 af[4], bfr[4];
        #pragma unroll
        for (int m = 0; m < 4; ++m)
            af[m] = *(const bf16x8*)&As[(wr + m * 16 + fr) * 32 + fk];
        #pragma unroll
        for (int n = 0; n < 4; ++n)
            bfr[n] = *(const bf16x8*)&Bs[(wc + n * 16 + fr) * 32 + fk];
        #pragma unroll
        for (int m = 0; m < 4; ++m)
            #pragma unroll
            for (int n = 0; n < 4; ++n)
                acc[m][n] = __builtin_amdgcn_mfma_f32_16x16x32_bf16(af[m], bfr[n], acc[m][n], 0, 0, 0);
        __syncthreads();
    }

    for (int ch = 0; ch < 4; ++ch) {
        if ((w & 1) == (ch >> 1)) {
            int nb = (ch & 1) * 2;
            #pragma unroll
            for (int n2 = 0; n2 < 2; ++n2)
                #pragma unroll
                for (int m = 0; m < 4; ++m)
                    #pragma unroll
                    for (int q = 0; q < 4; ++q)
                        Ct[(wr + m * 16 + (l >> 4) * 4 + q) * 34 + n2 * 16 + fr]
                            = acc[m][nb + n2][q];
        }
        __syncthreads();
        {
            int r = t >> 1, seg = (t & 1) * 16;
            int gi = iBase + r;
            size_t base = ((size_t)b * S_ + gi) * DATT + nBase + ch * 32 + seg;
            #pragma unroll
            for (int u = 0; u < 4; ++u) {
                float4 vv = *(float4*)&Ct[r * 34 + seg + 4 * u];
                *(float4*)&ctx[base + 4 * u] = vv;
            }
        }
        __syncthreads();
    }
}

// ---- K4b: context from fp32 weights (ws-constrained fallback) ----
__global__ __launch_bounds__(256) void k_ctx_f32(
    const float* __restrict__ wts, const short* __restrict__ Vt,
    float* __restrict__ ctx)
{
    __shared__ short As[128 * 40];
    __shared__ short Bs[128 * 32];
    int t = threadIdx.x;
    int l = t & 63, w = t >> 6;
    int wr = (w >> 1) * 64, wc = (w & 1) * 64;
    int fr = l & 15, fk = (l >> 4) * 8;
    int b = blockIdx.z;
    int iBase = blockIdx.y * 128;
    int nBase = blockIdx.x * 128;
    const float* Wp = wts + (size_t)b * S_ * S_;
    const short* Bp = Vt + (size_t)b * DATT * S_;

    f32x4 acc[4][4] = {};
    int trA = t >> 3, tcA = (t & 7) * 4;
    int srow = w * 16 + (l >> 2), skol = (l & 3) * 8;

    for (int k0 = 0; k0 < S_; k0 += 32) {
        #pragma unroll
        for (int it = 0; it < 2; ++it) {
            int r = it * 64 + srow;
            __builtin_amdgcn_global_load_lds(
                (const __attribute__((address_space(1))) void*)
                    &Bp[(size_t)(nBase + r) * S_ + k0 + skol],
                (__attribute__((address_space(3))) void*)
                    &Bs[(it * 64 + w * 16) * 32],
                16, 0, 0);
        }
        #pragma unroll
        for (int ii = 0; ii < 4; ++ii) {
            int r = trA + 32 * ii;
            float4 v = *(const float4*)&Wp[(size_t)(iBase + r) * S_ + k0 + tcA];
            short4 s4 = make_short4(f2bf(v.x), f2bf(v.y), f2bf(v.z), f2bf(v.w));
            *(short4*)&As[r * 40 + tcA] = s4;
        }
        __syncthreads();
        bf16x8 af[4], bfr[4];
        #pragma unroll
        for (int m = 0; m < 4; ++m)
            af[m] = *(const bf16x8*)&As[(wr + m * 16 + fr) * 40 + fk];
        #pragma unroll
        for (int n = 0; n < 4; ++n)
            bfr[n] = *(const bf16x8*)&Bs[(wc + n * 16 + fr) * 32 + fk];
        #pragma unroll
        for (int m = 0; m < 4; ++m)
            #pragma unroll
            for (int n = 0; n < 4; ++n)
                acc[m][n] = __builtin_amdgcn_mfma_f32_16x16x32_bf16(af[m], bfr[n], acc[m][n], 0, 0, 0);
        __syncthreads();
    }

    for (int m = 0; m < 4; ++m) {
        for (int q = 0; q < 4; ++q) {
            int i = iBase + wr + m * 16 + (l >> 4) * 4 + q;
            for (int n = 0; n < 4; ++n) {
                int d = nBase + wc + n * 16 + fr;
                ctx[((size_t)b * S_ + i) * DATT + d] = acc[m][n][q];
            }
        }
    }
}

extern "C" void kernel_launch(void* const* d_in, const int* in_sizes, int n_in,
                              void* d_out, int out_size, void* d_ws, size_t ws_size,
                              hipStream_t stream) {
    const float* query = (const float*)d_in[0];
    const float* key   = (const float*)d_in[1];
    const float* value = (const float*)d_in[2];
    const int*   mask  = (const int*)d_in[3];
    const float* Wq = (const float*)d_in[4];
    const float* bq = (const float*)d_in[5];
    const float* Wk = (const float*)d_in[6];
    const float* bk = (const float*)d_in[7];
    const float* Wv = (const float*)d_in[8];
    const float* bv = (const float*)d_in[9];

    float* ctx = (float*)d_out;                    // B*S*DATT fp32
    float* wts = ctx + (size_t)B_ * S_ * DATT;     // B*S*S fp32

    char* ws = (char*)d_ws;
    const size_t SZ_QKV = (size_t)B_ * S_ * DATT * 2;      // 16.78 MB
    const size_t SZ_WT  = (size_t)DATT * DIN * 2;          // 512 KB
    const size_t SZ_TAB = (size_t)S_ * 256 * 4;            // 2 MB
    short* Qb   = (short*)(ws);
    short* Kb   = (short*)(ws + SZ_QKV);
    short* Vt   = (short*)(ws + 2 * SZ_QKV);
    short* WtQ  = (short*)(ws + 3 * SZ_QKV);
    short* WtK  = (short*)(ws + 3 * SZ_QKV + SZ_WT);
    short* WtV  = (short*)(ws + 3 * SZ_QKV + 2 * SZ_WT);
    float* cosT = (float*)(ws + 3 * SZ_QKV + 3 * SZ_WT);
    float* sinT = (float*)(ws + 3 * SZ_QKV + 3 * SZ_WT + SZ_TAB);
    char*  big  = ws + 3 * SZ_QKV + 3 * SZ_WT + 2 * SZ_TAB;
    short* Vb   = (short*)big;                              // dead after k_vt
    short* Pb   = (short*)big;                              // written after k_vt
    const size_t needA = 3 * SZ_QKV + 3 * SZ_WT + 2 * SZ_TAB
                       + (size_t)B_ * S_ * S_ * 2;          // ~123.2 MB
    int usePb = ws_size >= needA ? 1 : 0;

    k_tables<<<dim3((S_ * 128) / 256), 256, 0, stream>>>(cosT, sinT);
    k_wt<<<dim3(64, 3), 256, 0, stream>>>(Wq, Wk, Wv, WtQ, WtK, WtV);
    k_proj<<<dim3(4, 128), 256, 0, stream>>>(query, WtQ, bq, Qb, cosT, sinT, 1);
    k_proj<<<dim3(4, 128), 256, 0, stream>>>(key,   WtK, bk, Kb, cosT, sinT, 1);
    k_proj<<<dim3(4, 128), 256, 0, stream>>>(value, WtV, bv, Vb, cosT, sinT, 0);
    k_vt<<<dim3(8, 32, 8), 256, 0, stream>>>(Vb, Vt);
    k_scores<<<dim3(16, 16, 8), 256, 0, stream>>>(Qb, Kb, mask, wts);
    k_softmax<<<dim3(B_ * S_), 256, 0, stream>>>(wts, Pb, usePb);
    if (usePb)
        k_ctx_bf16<<<dim3(4, 16, 8), 256, 0, stream>>>(Pb, Vt, ctx);
    else
        k_ctx_f32<<<dim3(4, 16, 8), 256, 0, stream>>>(wts, Vt, ctx);
}

// Round 6
// 542.540 us; speedup vs baseline: 1.3103x; 1.0936x over previous
//
#include <hip/hip_runtime.h>
#include <hip/hip_bf16.h>
#include <hip/hip_fp16.h>

#define B_   8
#define S_   2048
#define DIN  512
#define DATT 512
#define DROT 256

typedef __attribute__((ext_vector_type(4))) float f32x4;
typedef __attribute__((ext_vector_type(8))) short bf16x8;
typedef __attribute__((ext_vector_type(8))) unsigned short u16x8;

__device__ __forceinline__ short f2bf(float f) {
    __hip_bfloat16 h = __float2bfloat16(f);
    return *reinterpret_cast<short*>(&h);
}
__device__ __forceinline__ unsigned short f2h(float f) {
    __half h = __float2half(f);
    return *reinterpret_cast<unsigned short*>(&h);
}
__device__ __forceinline__ float h2f(unsigned short u) {
    __half h = *reinterpret_cast<__half*>(&u);
    return __half2float(h);
}

// ---- K0: rotary cos/sin tables ----
__global__ void k_tables(float* __restrict__ cosT, float* __restrict__ sinT) {
    int idx = blockIdx.x * 256 + threadIdx.x;
    if (idx >= S_ * 128) return;
    int s = idx >> 7;
    int i = idx & 127;
    float e    = (float)(2 * i) / (float)DROT;
    float invf = 1.0f / powf(10000.0f, e);
    float f    = (float)s * invf;
    float c = cosf(f), sn = sinf(f);
    cosT[s * 256 + 2 * i]     = c;
    cosT[s * 256 + 2 * i + 1] = c;
    sinT[s * 256 + 2 * i]     = sn;
    sinT[s * 256 + 2 * i + 1] = sn;
}

// ---- K0b: W(512x512 fp32) -> Wt bf16 [n][k], 3 matrices ----
__global__ __launch_bounds__(256) void k_wt(
    const float* __restrict__ Wq, const float* __restrict__ Wk,
    const float* __restrict__ Wv,
    short* __restrict__ WtQ, short* __restrict__ WtK, short* __restrict__ WtV)
{
    const float* W; short* Wt;
    if (blockIdx.y == 0)      { W = Wq; Wt = WtQ; }
    else if (blockIdx.y == 1) { W = Wk; Wt = WtK; }
    else                      { W = Wv; Wt = WtV; }
    int kt = blockIdx.x & 7, nt = blockIdx.x >> 3;
    int k0 = kt * 64, n0 = nt * 64;
    __shared__ float tile[64 * 68];
    int t = threadIdx.x;
    #pragma unroll
    for (int i = 0; i < 4; ++i) {
        int slot = t + 256 * i;
        int row = slot >> 4;
        int c4  = (slot & 15) * 4;
        float4 v = *(const float4*)&W[(size_t)(k0 + row) * DATT + n0 + c4];
        *(float4*)&tile[row * 68 + c4] = v;
    }
    __syncthreads();
    int nr = t >> 2, kq = (t & 3) * 16;
    bf16x8 o0, o1;
    #pragma unroll
    for (int j = 0; j < 8; ++j) o0[j] = f2bf(tile[(kq + j) * 68 + nr]);
    #pragma unroll
    for (int j = 0; j < 8; ++j) o1[j] = f2bf(tile[(kq + 8 + j) * 68 + nr]);
    *(bf16x8*)&Wt[(size_t)(n0 + nr) * DIN + k0 + kq]     = o0;
    *(bf16x8*)&Wt[(size_t)(n0 + nr) * DIN + k0 + kq + 8] = o1;
}

// ---- K1: merged QKV projection: z picks matrix; rotary for z<2 ----
__global__ __launch_bounds__(256) void k_proj3(
    const float* __restrict__ Xq, const float* __restrict__ Xk,
    const float* __restrict__ Xv, const short* __restrict__ Wt0,
    const float* __restrict__ bq, const float* __restrict__ bk,
    const float* __restrict__ bv,
    short* __restrict__ Qb, short* __restrict__ Kb, short* __restrict__ Vb,
    const float* __restrict__ cosT, const float* __restrict__ sinT)
{
    int z = blockIdx.z;
    const float* X    = (z == 0) ? Xq : (z == 1) ? Xk : Xv;
    const float* bias = (z == 0) ? bq : (z == 1) ? bk : bv;
    short*       Out  = (z == 0) ? Qb : (z == 1) ? Kb : Vb;
    const short* Wt   = Wt0 + (size_t)z * DATT * DIN;
    int doRot = (z < 2);

    __shared__ __align__(16) float smem[4608];     // 18432 B
    short* As = (short*)smem;                      // 128*40 shorts
    short* Bs = (short*)(smem + 2560);             // 128*32 shorts
    float* Ct = smem;                              // 128*34 floats
    int t = threadIdx.x;
    int l = t & 63, w = t >> 6;
    int wr = (w >> 1) * 64, wc = (w & 1) * 64;
    int fr = l & 15, fk = (l >> 4) * 8;
    int rowBase = blockIdx.y * 128;
    int nBase   = blockIdx.x * 128;

    f32x4 acc[4][4] = {};
    int trA = t >> 3, tcA = (t & 7) * 4;
    int srow = w * 16 + (l >> 2), skol = (l & 3) * 8;

    for (int k0 = 0; k0 < DIN; k0 += 32) {
        #pragma unroll
        for (int it = 0; it < 2; ++it) {
            int r = it * 64 + srow;
            __builtin_amdgcn_global_load_lds(
                (const __attribute__((address_space(1))) void*)
                    &Wt[(size_t)(nBase + r) * DIN + k0 + skol],
                (__attribute__((address_space(3))) void*)
                    &Bs[(it * 64 + w * 16) * 32],
                16, 0, 0);
        }
        #pragma unroll
        for (int ii = 0; ii < 4; ++ii) {
            int r = trA + 32 * ii;
            float4 v = *(const float4*)&X[(size_t)(rowBase + r) * DIN + k0 + tcA];
            short4 s4 = make_short4(f2bf(v.x), f2bf(v.y), f2bf(v.z), f2bf(v.w));
            *(short4*)&As[r * 40 + tcA] = s4;
        }
        __syncthreads();
        bf16x8 af[4], bfr[4];
        #pragma unroll
        for (int m = 0; m < 4; ++m)
            af[m] = *(const bf16x8*)&As[(wr + m * 16 + fr) * 40 + fk];
        #pragma unroll
        for (int n = 0; n < 4; ++n)
            bfr[n] = *(const bf16x8*)&Bs[(wc + n * 16 + fr) * 32 + fk];
        #pragma unroll
        for (int m = 0; m < 4; ++m)
            #pragma unroll
            for (int n = 0; n < 4; ++n)
                acc[m][n] = __builtin_amdgcn_mfma_f32_16x16x32_bf16(af[m], bfr[n], acc[m][n], 0, 0, 0);
        __syncthreads();
    }

    for (int ch = 0; ch < 4; ++ch) {
        if ((w & 1) == (ch >> 1)) {
            int nb = (ch & 1) * 2;
            #pragma unroll
            for (int n2 = 0; n2 < 2; ++n2)
                #pragma unroll
                for (int m = 0; m < 4; ++m)
                    #pragma unroll
                    for (int q = 0; q < 4; ++q)
                        Ct[(wr + m * 16 + (l >> 4) * 4 + q) * 34 + n2 * 16 + fr]
                            = acc[m][nb + n2][q];
        }
        __syncthreads();
        {
            int r = t >> 1, seg = (t & 1) * 16;
            int rg = rowBase + r;
            int cg = nBase + ch * 32 + seg;
            float vv[16];
            #pragma unroll
            for (int u = 0; u < 4; ++u)
                *(float4*)&vv[4 * u] = *(float4*)&Ct[r * 34 + seg + 4 * u];
            #pragma unroll
            for (int u = 0; u < 4; ++u) {
                float4 bb = *(const float4*)&bias[cg + 4 * u];
                vv[4 * u + 0] += bb.x; vv[4 * u + 1] += bb.y;
                vv[4 * u + 2] += bb.z; vv[4 * u + 3] += bb.w;
            }
            if (doRot && cg < DROT) {
                int s = rg & (S_ - 1);
                float cs[16], sn[16];
                #pragma unroll
                for (int u = 0; u < 4; ++u) {
                    *(float4*)&cs[4 * u] = *(const float4*)&cosT[s * 256 + cg + 4 * u];
                    *(float4*)&sn[4 * u] = *(const float4*)&sinT[s * 256 + cg + 4 * u];
                }
                #pragma unroll
                for (int j = 0; j < 16; j += 2) {
                    float x1 = vv[j], x2 = vv[j + 1];
                    vv[j]     = x1 * cs[j]     - x2 * sn[j];
                    vv[j + 1] = x2 * cs[j + 1] + x1 * sn[j + 1];
                }
            }
            bf16x8 o0, o1;
            #pragma unroll
            for (int j = 0; j < 8; ++j) { o0[j] = f2bf(vv[j]); o1[j] = f2bf(vv[8 + j]); }
            *(bf16x8*)&Out[(size_t)rg * DATT + cg]     = o0;
            *(bf16x8*)&Out[(size_t)rg * DATT + cg + 8] = o1;
        }
        __syncthreads();
    }
}

// ---- K1b: Vb[2048][512] -> Vt[512][2048] bf16, per batch ----
__global__ __launch_bounds__(256) void k_vt(
    const short* __restrict__ Vb, short* __restrict__ Vt)
{
    int b = blockIdx.z;
    int d0 = blockIdx.x * 64;
    int r0 = blockIdx.y * 64;
    const short* Vp = Vb + (size_t)b * S_ * DATT;
    short* Tp = Vt + (size_t)b * DATT * S_;
    __shared__ short tile[64 * 66];
    int t = threadIdx.x;
    #pragma unroll
    for (int i = 0; i < 2; ++i) {
        int slot = t + 256 * i;
        int row = slot >> 3;
        int c8  = (slot & 7) * 8;
        bf16x8 v = *(const bf16x8*)&Vp[(size_t)(r0 + row) * DATT + d0 + c8];
        #pragma unroll
        for (int j = 0; j < 8; ++j) tile[row * 66 + c8 + j] = v[j];
    }
    __syncthreads();
    int dr = t >> 2, rq = (t & 3) * 16;
    bf16x8 o0, o1;
    #pragma unroll
    for (int j = 0; j < 8; ++j) o0[j] = tile[(rq + j) * 66 + dr];
    #pragma unroll
    for (int j = 0; j < 8; ++j) o1[j] = tile[(rq + 8 + j) * 66 + dr];
    *(bf16x8*)&Tp[(size_t)(d0 + dr) * S_ + r0 + rq]     = o0;
    *(bf16x8*)&Tp[(size_t)(d0 + dr) * S_ + r0 + rq + 8] = o1;
}

// ---- K2a: scores = Q @ K^T * scale -> fp16 raw (no mask) into ws ----
__global__ __launch_bounds__(256) void k_scores_h(
    const short* __restrict__ Qb, const short* __restrict__ Kb,
    unsigned short* __restrict__ Sraw)
{
    __shared__ __align__(16) float smem[4352];
    short* As = (short*)smem;
    short* Bs = (short*)(smem + 2048);
    float* Ct = smem;
    int t = threadIdx.x;
    int l = t & 63, w = t >> 6;
    int wr = (w >> 1) * 64, wc = (w & 1) * 64;
    int fr = l & 15, fk = (l >> 4) * 8;
    int b = blockIdx.z;
    int iBase = blockIdx.y * 128;
    int jBase = blockIdx.x * 128;
    const short* Qp = Qb + (size_t)b * S_ * DATT;
    const short* Kp = Kb + (size_t)b * S_ * DATT;

    f32x4 acc[4][4] = {};
    int srow = w * 16 + (l >> 2);
    int skol = (l & 3) * 8;

    for (int k0 = 0; k0 < DATT; k0 += 32) {
        #pragma unroll
        for (int it = 0; it < 2; ++it) {
            int r = it * 64 + srow;
            __builtin_amdgcn_global_load_lds(
                (const __attribute__((address_space(1))) void*)
                    &Qp[(size_t)(iBase + r) * DATT + k0 + skol],
                (__attribute__((address_space(3))) void*)
                    &As[(it * 64 + w * 16) * 32],
                16, 0, 0);
            __builtin_amdgcn_global_load_lds(
                (const __attribute__((address_space(1))) void*)
                    &Kp[(size_t)(jBase + r) * DATT + k0 + skol],
                (__attribute__((address_space(3))) void*)
                    &Bs[(it * 64 + w * 16) * 32],
                16, 0, 0);
        }
        __syncthreads();
        bf16x8 af[4], bfr[4];
        #pragma unroll
        for (int m = 0; m < 4; ++m)
            af[m] = *(const bf16x8*)&As[(wr + m * 16 + fr) * 32 + fk];
        #pragma unroll
        for (int n = 0; n < 4; ++n)
            bfr[n] = *(const bf16x8*)&Bs[(wc + n * 16 + fr) * 32 + fk];
        #pragma unroll
        for (int m = 0; m < 4; ++m)
            #pragma unroll
            for (int n = 0; n < 4; ++n)
                acc[m][n] = __builtin_amdgcn_mfma_f32_16x16x32_bf16(af[m], bfr[n], acc[m][n], 0, 0, 0);
        __syncthreads();
    }

    const float scale = 0.04419417382415922f;   // 1/sqrt(512)
    for (int ch = 0; ch < 4; ++ch) {
        if ((w & 1) == (ch >> 1)) {
            int nb = (ch & 1) * 2;
            #pragma unroll
            for (int n2 = 0; n2 < 2; ++n2)
                #pragma unroll
                for (int m = 0; m < 4; ++m)
                    #pragma unroll
                    for (int q = 0; q < 4; ++q)
                        Ct[(wr + m * 16 + (l >> 4) * 4 + q) * 34 + n2 * 16 + fr]
                            = acc[m][nb + n2][q] * scale;
        }
        __syncthreads();
        {
            int r = t >> 1, seg = (t & 1) * 16;
            size_t base = ((size_t)b * S_ + iBase + r) * S_ + jBase + ch * 32 + seg;
            float vv[16];
            #pragma unroll
            for (int u = 0; u < 4; ++u)
                *(float4*)&vv[4 * u] = *(float4*)&Ct[r * 34 + seg + 4 * u];
            u16x8 h0, h1;
            #pragma unroll
            for (int j = 0; j < 8; ++j) { h0[j] = f2h(vv[j]); h1[j] = f2h(vv[8 + j]); }
            *(u16x8*)&Sraw[base]     = h0;
            *(u16x8*)&Sraw[base + 8] = h1;
        }
        __syncthreads();
    }
}

// ---- K3a: softmax: fp16 raw + mask -> fp32 weights + bf16 Pb (in place) ----
__global__ __launch_bounds__(256) void k_softmax_h(
    unsigned short* __restrict__ SrawPb, const int* __restrict__ mask,
    float* __restrict__ wts)
{
    size_t row = blockIdx.x;
    unsigned short* sp = SrawPb + row * S_;
    const int* mp = mask + row * S_;
    float* wp = wts + row * S_;
    int t = threadIdx.x, l = t & 63, w = t >> 6;

    u16x8 raw = *(const u16x8*)&sp[8 * t];
    int4 m0 = *(const int4*)&mp[8 * t];
    int4 m1 = *(const int4*)&mp[8 * t + 4];
    float v[8];
    v[0] = (m0.x == 0) ? -1e-9f : h2f(raw[0]);
    v[1] = (m0.y == 0) ? -1e-9f : h2f(raw[1]);
    v[2] = (m0.z == 0) ? -1e-9f : h2f(raw[2]);
    v[3] = (m0.w == 0) ? -1e-9f : h2f(raw[3]);
    v[4] = (m1.x == 0) ? -1e-9f : h2f(raw[4]);
    v[5] = (m1.y == 0) ? -1e-9f : h2f(raw[5]);
    v[6] = (m1.z == 0) ? -1e-9f : h2f(raw[6]);
    v[7] = (m1.w == 0) ? -1e-9f : h2f(raw[7]);

    float mx = v[0];
    #pragma unroll
    for (int j = 1; j < 8; ++j) mx = fmaxf(mx, v[j]);
    for (int off = 32; off; off >>= 1) mx = fmaxf(mx, __shfl_xor(mx, off));
    __shared__ float red[8];
    if (l == 0) red[w] = mx;
    __syncthreads();
    mx = fmaxf(fmaxf(red[0], red[1]), fmaxf(red[2], red[3]));
    float sum = 0.f;
    #pragma unroll
    for (int j = 0; j < 8; ++j) { v[j] = expf(v[j] - mx); sum += v[j]; }
    for (int off = 32; off; off >>= 1) sum += __shfl_xor(sum, off);
    if (l == 0) red[4 + w] = sum;
    __syncthreads();
    sum = red[4] + red[5] + red[6] + red[7];
    float inv = 1.0f / sum;
    #pragma unroll
    for (int j = 0; j < 8; ++j) v[j] *= inv;

    *(float4*)&wp[8 * t]     = make_float4(v[0], v[1], v[2], v[3]);
    *(float4*)&wp[8 * t + 4] = make_float4(v[4], v[5], v[6], v[7]);
    bf16x8 pb8;
    #pragma unroll
    for (int j = 0; j < 8; ++j) pb8[j] = f2bf(v[j]);
    *(bf16x8*)&sp[8 * t] = pb8;   // Pb overwrites Sraw in place
}

// ---- K4a: context = Pb(bf16) @ Vt^T; LDS-transpose epilogue ----
__global__ __launch_bounds__(256) void k_ctx_bf16(
    const short* __restrict__ Pb, const short* __restrict__ Vt,
    float* __restrict__ ctx)
{
    __shared__ __align__(16) float smem[4352];
    short* As = (short*)smem;
    short* Bs = (short*)(smem + 2048);
    float* Ct = smem;
    int t = threadIdx.x;
    int l = t & 63, w = t >> 6;
    int wr = (w >> 1) * 64, wc = (w & 1) * 64;
    int fr = l & 15, fk = (l >> 4) * 8;
    int b = blockIdx.z;
    int iBase = blockIdx.y * 128;
    int nBase = blockIdx.x * 128;
    const short* Ap = Pb + (size_t)b * S_ * S_;
    const short* Bp = Vt + (size_t)b * DATT * S_;

    f32x4 acc[4][4] = {};
    int srow = w * 16 + (l >> 2);
    int skol = (l & 3) * 8;

    for (int k0 = 0; k0 < S_; k0 += 32) {
        #pragma unroll
        for (int it = 0; it < 2; ++it) {
            int r = it * 64 + srow;
            __builtin_amdgcn_global_load_lds(
                (const __attribute__((address_space(1))) void*)
                    &Ap[(size_t)(iBase + r) * S_ + k0 + skol],
                (__attribute__((address_space(3))) void*)
                    &As[(it * 64 + w * 16) * 32],
                16, 0, 0);
            __builtin_amdgcn_global_load_lds(
                (const __attribute__((address_space(1))) void*)
                    &Bp[(size_t)(nBase + r) * S_ + k0 + skol],
                (__attribute__((address_space(3))) void*)
                    &Bs[(it * 64 + w * 16) * 32],
                16, 0, 0);
        }
        __syncthreads();
        bf16x8 af[4], bfr[4];
        #pragma unroll
        for (int m = 0; m < 4; ++m)
            af[m] = *(const bf16x8*)&As[(wr + m * 16 + fr) * 32 + fk];
        #pragma unroll
        for (int n = 0; n < 4; ++n)
            bfr[n] = *(const bf16x8*)&Bs[(wc + n * 16 + fr) * 32 + fk];
        #pragma unroll
        for (int m = 0; m < 4; ++m)
            #pragma unroll
            for (int n = 0; n < 4; ++n)
                acc[m][n] = __builtin_amdgcn_mfma_f32_16x16x32_bf16(af[m], bfr[n], acc[m][n], 0, 0, 0);
        __syncthreads();
    }

    for (int ch = 0; ch < 4; ++ch) {
        if ((w & 1) == (ch >> 1)) {
            int nb = (ch & 1) * 2;
            #pragma unroll
            for (int n2 = 0; n2 < 2; ++n2)
                #pragma unroll
                for (int m = 0; m < 4; ++m)
                    #pragma unroll
                    for (int q = 0; q < 4; ++q)
                        Ct[(wr + m * 16 + (l >> 4) * 4 + q) * 34 + n2 * 16 + fr]
                            = acc[m][nb + n2][q];
        }
        __syncthreads();
        {
            int r = t >> 1, seg = (t & 1) * 16;
            int gi = iBase + r;
            size_t base = ((size_t)b * S_ + gi) * DATT + nBase + ch * 32 + seg;
            #pragma unroll
            for (int u = 0; u < 4; ++u) {
                float4 vv = *(float4*)&Ct[r * 34 + seg + 4 * u];
                *(float4*)&ctx[base + 4 * u] = vv;
            }
        }
        __syncthreads();
    }
}

// ================= fallback path (small ws): fp32 scores in d_out =========
__global__ __launch_bounds__(256) void k_scores_f32(
    const short* __restrict__ Qb, const short* __restrict__ Kb,
    const int* __restrict__ mask, float* __restrict__ wOut)
{
    __shared__ __align__(16) float smem[4352];
    short* As = (short*)smem;
    short* Bs = (short*)(smem + 2048);
    float* Ct = smem;
    int t = threadIdx.x;
    int l = t & 63, w = t >> 6;
    int wr = (w >> 1) * 64, wc = (w & 1) * 64;
    int fr = l & 15, fk = (l >> 4) * 8;
    int b = blockIdx.z;
    int iBase = blockIdx.y * 128;
    int jBase = blockIdx.x * 128;
    const short* Qp = Qb + (size_t)b * S_ * DATT;
    const short* Kp = Kb + (size_t)b * S_ * DATT;

    f32x4 acc[4][4] = {};
    int srow = w * 16 + (l >> 2);
    int skol = (l & 3) * 8;

    for (int k0 = 0; k0 < DATT; k0 += 32) {
        #pragma unroll
        for (int it = 0; it < 2; ++it) {
            int r = it * 64 + srow;
            __builtin_amdgcn_global_load_lds(
                (const __attribute__((address_space(1))) void*)
                    &Qp[(size_t)(iBase + r) * DATT + k0 + skol],
                (__attribute__((address_space(3))) void*)
                    &As[(it * 64 + w * 16) * 32],
                16, 0, 0);
            __builtin_amdgcn_global_load_lds(
                (const __attribute__((address_space(1))) void*)
                    &Kp[(size_t)(jBase + r) * DATT + k0 + skol],
                (__attribute__((address_space(3))) void*)
                    &Bs[(it * 64 + w * 16) * 32],
                16, 0, 0);
        }
        __syncthreads();
        bf16x8 af[4], bfr[4];
        #pragma unroll
        for (int m = 0; m < 4; ++m)
            af[m] = *(const bf16x8*)&As[(wr + m * 16 + fr) * 32 + fk];
        #pragma unroll
        for (int n = 0; n < 4; ++n)
            bfr[n] = *(const bf16x8*)&Bs[(wc + n * 16 + fr) * 32 + fk];
        #pragma unroll
        for (int m = 0; m < 4; ++m)
            #pragma unroll
            for (int n = 0; n < 4; ++n)
                acc[m][n] = __builtin_amdgcn_mfma_f32_16x16x32_bf16(af[m], bfr[n], acc[m][n], 0, 0, 0);
        __syncthreads();
    }

    const float scale = 0.04419417382415922f;
    for (int ch = 0; ch < 4; ++ch) {
        if ((w & 1) == (ch >> 1)) {
            int nb = (ch & 1) * 2;
            #pragma unroll
            for (int n2 = 0; n2 < 2; ++n2)
                #pragma unroll
                for (int m = 0; m < 4; ++m)
                    #pragma unroll
                    for (int q = 0; q < 4; ++q)
                        Ct[(wr + m * 16 + (l >> 4) * 4 + q) * 34 + n2 * 16 + fr]
                            = acc[m][nb + n2][q] * scale;
        }
        __syncthreads();
        {
            int r = t >> 1, seg = (t & 1) * 16;
            size_t base = ((size_t)b * S_ + iBase + r) * S_ + jBase + ch * 32 + seg;
            #pragma unroll
            for (int u = 0; u < 4; ++u) {
                float4 vv = *(float4*)&Ct[r * 34 + seg + 4 * u];
                int4  mm = *(const int4*)&mask[base + 4 * u];
                vv.x = (mm.x == 0) ? -1e-9f : vv.x;
                vv.y = (mm.y == 0) ? -1e-9f : vv.y;
                vv.z = (mm.z == 0) ? -1e-9f : vv.z;
                vv.w = (mm.w == 0) ? -1e-9f : vv.w;
                *(float4*)&wOut[base + 4 * u] = vv;
            }
        }
        __syncthreads();
    }
}

__global__ __launch_bounds__(256) void k_softmax_f32(float* __restrict__ wts) {
    size_t row = blockIdx.x;
    float* p = wts + row * S_;
    int t = threadIdx.x, l = t & 63, w = t >> 6;
    float v[8];
    *(float4*)&v[0] = ((const float4*)p)[t];
    *(float4*)&v[4] = ((const float4*)p)[t + 256];
    float mx = v[0];
    #pragma unroll
    for (int j = 1; j < 8; ++j) mx = fmaxf(mx, v[j]);
    for (int off = 32; off; off >>= 1) mx = fmaxf(mx, __shfl_xor(mx, off));
    __shared__ float red[8];
    if (l == 0) red[w] = mx;
    __syncthreads();
    mx = fmaxf(fmaxf(red[0], red[1]), fmaxf(red[2], red[3]));
    float sum = 0.f;
    #pragma unroll
    for (int j = 0; j < 8; ++j) { v[j] = expf(v[j] - mx); sum += v[j]; }
    for (int off = 32; off; off >>= 1) sum += __shfl_xor(sum, off);
    if (l == 0) red[4 + w] = sum;
    __syncthreads();
    sum = red[4] + red[5] + red[6] + red[7];
    float inv = 1.0f / sum;
    #pragma unroll
    for (int j = 0; j < 8; ++j) v[j] *= inv;
    ((float4*)p)[t]       = *(float4*)&v[0];
    ((float4*)p)[t + 256] = *(float4*)&v[4];
}

__global__ __launch_bounds__(256) void k_ctx_f32(
    const float* __restrict__ wts, const short* __restrict__ Vt,
    float* __restrict__ ctx)
{
    __shared__ short As[128 * 40];
    __shared__ short Bs[128 * 32];
    int t = threadIdx.x;
    int l = t & 63, w = t >> 6;
    int wr = (w >> 1) * 64, wc = (w & 1) * 64;
    int fr = l & 15, fk = (l >> 4) * 8;
    int b = blockIdx.z;
    int iBase = blockIdx.y * 128;
    int nBase = blockIdx.x * 128;
    const float* Wp = wts + (size_t)b * S_ * S_;
    const short* Bp = Vt + (size_t)b * DATT * S_;

    f32x4 acc[4][4] = {};
    int trA = t >> 3, tcA = (t & 7) * 4;
    int srow = w * 16 + (l >> 2), skol = (l & 3) * 8;

    for (int k0 = 0; k0 < S_; k0 += 32) {
        #pragma unroll
        for (int it = 0; it < 2; ++it) {
            int r = it * 64 + srow;
            __builtin_amdgcn_global_load_lds(
                (const __attribute__((address_space(1))) void*)
                    &Bp[(size_t)(nBase + r) * S_ + k0 + skol],
                (__attribute__((address_space(3))) void*)
                    &Bs[(it * 64 + w * 16) * 32],
                16, 0, 0);
        }
        #pragma unroll
        for (int ii = 0; ii < 4; ++ii) {
            int r = trA + 32 * ii;
            float4 v = *(const float4*)&Wp[(size_t)(iBase + r) * S_ + k0 + tcA];
            short4 s4 = make_short4(f2bf(v.x), f2bf(v.y), f2bf(v.z), f2bf(v.w));
            *(short4*)&As[r * 40 + tcA] = s4;
        }
        __syncthreads();
        bf16x8 af[4], bfr[4];
        #pragma unroll
        for (int m = 0; m < 4; ++m)
            af[m] = *(const bf16x8*)&As[(wr + m * 16 + fr) * 40 + fk];
        #pragma unroll
        for (int n = 0; n < 4; ++n)
            bfr[n] = *(const bf16x8*)&Bs[(wc + n * 16 + fr) * 32 + fk];
        #pragma unroll
        for (int m = 0; m < 4; ++m)
            #pragma unroll
            for (int n = 0; n < 4; ++n)
                acc[m][n] = __builtin_amdgcn_mfma_f32_16x16x32_bf16(af[m], bfr[n], acc[m][n], 0, 0, 0);
        __syncthreads();
    }

    for (int m = 0; m < 4; ++m) {
        for (int q = 0; q < 4; ++q) {
            int i = iBase + wr + m * 16 + (l >> 4) * 4 + q;
            for (int n = 0; n < 4; ++n) {
                int d = nBase + wc + n * 16 + fr;
                ctx[((size_t)b * S_ + i) * DATT + d] = acc[m][n][q];
            }
        }
    }
}

extern "C" void kernel_launch(void* const* d_in, const int* in_sizes, int n_in,
                              void* d_out, int out_size, void* d_ws, size_t ws_size,
                              hipStream_t stream) {
    const float* query = (const float*)d_in[0];
    const float* key   = (const float*)d_in[1];
    const float* value = (const float*)d_in[2];
    const int*   mask  = (const int*)d_in[3];
    const float* Wq = (const float*)d_in[4];
    const float* bq = (const float*)d_in[5];
    const float* Wk = (const float*)d_in[6];
    const float* bk = (const float*)d_in[7];
    const float* Wv = (const float*)d_in[8];
    const float* bv = (const float*)d_in[9];

    float* ctx = (float*)d_out;                    // B*S*DATT fp32
    float* wts = ctx + (size_t)B_ * S_ * DATT;     // B*S*S fp32

    char* ws = (char*)d_ws;
    const size_t SZ_QKV = (size_t)B_ * S_ * DATT * 2;      // 16.78 MB
    const size_t SZ_WT  = (size_t)DATT * DIN * 2;          // 512 KB
    const size_t SZ_TAB = (size_t)S_ * 256 * 4;            // 2 MB
    short* Qb   = (short*)(ws);
    short* Kb   = (short*)(ws + SZ_QKV);
    short* Vt   = (short*)(ws + 2 * SZ_QKV);
    short* WtQ  = (short*)(ws + 3 * SZ_QKV);
    short* WtK  = (short*)(ws + 3 * SZ_QKV + SZ_WT);
    short* WtV  = (short*)(ws + 3 * SZ_QKV + 2 * SZ_WT);
    float* cosT = (float*)(ws + 3 * SZ_QKV + 3 * SZ_WT);
    float* sinT = (float*)(ws + 3 * SZ_QKV + 3 * SZ_WT + SZ_TAB);
    char*  big  = ws + 3 * SZ_QKV + 3 * SZ_WT + 2 * SZ_TAB;
    short* Vb   = (short*)big;                 // dead after k_vt
    unsigned short* Sraw = (unsigned short*)big;  // fp16 raw -> bf16 Pb in place
    const size_t needA = 3 * SZ_QKV + 3 * SZ_WT + 2 * SZ_TAB
                       + (size_t)B_ * S_ * S_ * 2;          // ~123.2 MB
    int useH = ws_size >= needA ? 1 : 0;

    k_tables<<<dim3((S_ * 128) / 256), 256, 0, stream>>>(cosT, sinT);
    k_wt<<<dim3(64, 3), 256, 0, stream>>>(Wq, Wk, Wv, WtQ, WtK, WtV);
    k_proj3<<<dim3(4, 128, 3), 256, 0, stream>>>(query, key, value, WtQ,
                                                 bq, bk, bv, Qb, Kb, Vb,
                                                 cosT, sinT);
    k_vt<<<dim3(8, 32, 8), 256, 0, stream>>>(Vb, Vt);
    if (useH) {
        k_scores_h<<<dim3(16, 16, 8), 256, 0, stream>>>(Qb, Kb, Sraw);
        k_softmax_h<<<dim3(B_ * S_), 256, 0, stream>>>(Sraw, mask, wts);
        k_ctx_bf16<<<dim3(4, 16, 8), 256, 0, stream>>>((short*)Sraw, Vt, ctx);
    } else {
        k_scores_f32<<<dim3(16, 16, 8), 256, 0, stream>>>(Qb, Kb, mask, wts);
        k_softmax_f32<<<dim3(B_ * S_), 256, 0, stream>>>(wts);
        k_ctx_f32<<<dim3(4, 16, 8), 256, 0, stream>>>(wts, Vt, ctx);
    }
}

// Round 10
// 524.260 us; speedup vs baseline: 1.3560x; 1.0349x over previous
//
#include <hip/hip_runtime.h>
#include <hip/hip_bf16.h>
#include <hip/hip_fp16.h>

#define B_   8
#define S_   2048
#define DIN  512
#define DATT 512
#define DROT 256

typedef __attribute__((ext_vector_type(4))) float f32x4;
typedef __attribute__((ext_vector_type(8))) short bf16x8;
typedef __attribute__((ext_vector_type(8))) unsigned short u16x8;

__device__ __forceinline__ short f2bf(float f) {
    __hip_bfloat16 h = __float2bfloat16(f);
    return *reinterpret_cast<short*>(&h);
}
__device__ __forceinline__ unsigned short f2h(float f) {
    __half h = __float2half(f);
    return *reinterpret_cast<unsigned short*>(&h);
}
__device__ __forceinline__ float h2f(unsigned short u) {
    __half h = *reinterpret_cast<__half*>(&u);
    return __half2float(h);
}

// ---- K0: rotary cos/sin tables ----
__global__ void k_tables(float* __restrict__ cosT, float* __restrict__ sinT) {
    int idx = blockIdx.x * 256 + threadIdx.x;
    if (idx >= S_ * 128) return;
    int s = idx >> 7;
    int i = idx & 127;
    float e    = (float)(2 * i) / (float)DROT;
    float invf = 1.0f / powf(10000.0f, e);
    float f    = (float)s * invf;
    float c = cosf(f), sn = sinf(f);
    cosT[s * 256 + 2 * i]     = c;
    cosT[s * 256 + 2 * i + 1] = c;
    sinT[s * 256 + 2 * i]     = sn;
    sinT[s * 256 + 2 * i + 1] = sn;
}

// ---- K0b: W(512x512 fp32) -> Wt bf16 [n][k], 3 matrices ----
__global__ __launch_bounds__(256) void k_wt(
    const float* __restrict__ Wq, const float* __restrict__ Wk,
    const float* __restrict__ Wv,
    short* __restrict__ WtQ, short* __restrict__ WtK, short* __restrict__ WtV)
{
    const float* W; short* Wt;
    if (blockIdx.y == 0)      { W = Wq; Wt = WtQ; }
    else if (blockIdx.y == 1) { W = Wk; Wt = WtK; }
    else                      { W = Wv; Wt = WtV; }
    int kt = blockIdx.x & 7, nt = blockIdx.x >> 3;
    int k0 = kt * 64, n0 = nt * 64;
    __shared__ float tile[64 * 68];
    int t = threadIdx.x;
    #pragma unroll
    for (int i = 0; i < 4; ++i) {
        int slot = t + 256 * i;
        int row = slot >> 4;
        int c4  = (slot & 15) * 4;
        float4 v = *(const float4*)&W[(size_t)(k0 + row) * DATT + n0 + c4];
        *(float4*)&tile[row * 68 + c4] = v;
    }
    __syncthreads();
    int nr = t >> 2, kq = (t & 3) * 16;
    bf16x8 o0, o1;
    #pragma unroll
    for (int j = 0; j < 8; ++j) o0[j] = f2bf(tile[(kq + j) * 68 + nr]);
    #pragma unroll
    for (int j = 0; j < 8; ++j) o1[j] = f2bf(tile[(kq + 8 + j) * 68 + nr]);
    *(bf16x8*)&Wt[(size_t)(n0 + nr) * DIN + k0 + kq]     = o0;
    *(bf16x8*)&Wt[(size_t)(n0 + nr) * DIN + k0 + kq + 8] = o1;
}

// ---- K1: merged QKV projection, BK=64, swizzled B staging ----
__global__ __launch_bounds__(256) void k_proj3(
    const float* __restrict__ Xq, const float* __restrict__ Xk,
    const float* __restrict__ Xv, const short* __restrict__ Wt0,
    const float* __restrict__ bq, const float* __restrict__ bk,
    const float* __restrict__ bv,
    short* __restrict__ Qb, short* __restrict__ Kb, short* __restrict__ Vb,
    const float* __restrict__ cosT, const float* __restrict__ sinT)
{
    int z = blockIdx.z;
    const float* X    = (z == 0) ? Xq : (z == 1) ? Xk : Xv;
    const float* bias = (z == 0) ? bq : (z == 1) ? bk : bv;
    short*       Out  = (z == 0) ? Qb : (z == 1) ? Kb : Vb;
    const short* Wt   = Wt0 + (size_t)z * DATT * DIN;
    int doRot = (z < 2);

    __shared__ __align__(16) float smem[8704];     // 34816 B
    short* As = (short*)smem;                      // 128*72 shorts = 18432 B
    short* Bs = (short*)(smem + 4608);             // 128*64 shorts = 16384 B
    float* Ct = smem;                              // 128*34 floats = 17408 B
    int t = threadIdx.x;
    int l = t & 63, w = t >> 6;
    int wr = (w >> 1) * 64, wc = (w & 1) * 64;
    int fr = l & 15, fk8 = (l >> 4) * 8;
    int xr = (fr & 7) << 3;                        // read-side XOR (shorts)
    int rowBase = blockIdx.y * 128;
    int nBase   = blockIdx.x * 128;

    f32x4 acc[4][4] = {};
    int trA = t >> 4, tcA = (t & 15) * 4;
    int srow = w * 8 + (l >> 3);
    int skolsw = (((l & 7) ^ (l >> 3)) * 8);       // pre-swizzled source col

    for (int k0 = 0; k0 < DIN; k0 += 64) {
        #pragma unroll
        for (int it = 0; it < 4; ++it) {
            int r = it * 32 + srow;
            __builtin_amdgcn_global_load_lds(
                (const __attribute__((address_space(1))) void*)
                    &Wt[(size_t)(nBase + r) * DIN + k0 + skolsw],
                (__attribute__((address_space(3))) void*)
                    &Bs[(it * 32 + w * 8) * 64],
                16, 0, 0);
        }
        #pragma unroll
        for (int ii = 0; ii < 8; ++ii) {
            int r = ii * 16 + trA;
            float4 v = *(const float4*)&X[(size_t)(rowBase + r) * DIN + k0 + tcA];
            short4 s4 = make_short4(f2bf(v.x), f2bf(v.y), f2bf(v.z), f2bf(v.w));
            *(short4*)&As[r * 72 + tcA] = s4;
        }
        __syncthreads();
        #pragma unroll
        for (int kk = 0; kk < 64; kk += 32) {
            bf16x8 af[4], bfr[4];
            #pragma unroll
            for (int m = 0; m < 4; ++m)
                af[m] = *(const bf16x8*)&As[(wr + m * 16 + fr) * 72 + kk + fk8];
            #pragma unroll
            for (int n = 0; n < 4; ++n)
                bfr[n] = *(const bf16x8*)&Bs[(wc + n * 16 + fr) * 64 + ((kk + fk8) ^ xr)];
            #pragma unroll
            for (int m = 0; m < 4; ++m)
                #pragma unroll
                for (int n = 0; n < 4; ++n)
                    acc[m][n] = __builtin_amdgcn_mfma_f32_16x16x32_bf16(af[m], bfr[n], acc[m][n], 0, 0, 0);
        }
        __syncthreads();
    }

    for (int ch = 0; ch < 4; ++ch) {
        if ((w & 1) == (ch >> 1)) {
            int nb = (ch & 1) * 2;
            #pragma unroll
            for (int n2 = 0; n2 < 2; ++n2)
                #pragma unroll
                for (int m = 0; m < 4; ++m)
                    #pragma unroll
                    for (int q = 0; q < 4; ++q)
                        Ct[(wr + m * 16 + (l >> 4) * 4 + q) * 34 + n2 * 16 + fr]
                            = acc[m][nb + n2][q];
        }
        __syncthreads();
        {
            int r = t >> 1, seg = (t & 1) * 16;
            int rg = rowBase + r;
            int cg = nBase + ch * 32 + seg;
            float vv[16];
            #pragma unroll
            for (int u = 0; u < 4; ++u)
                *(float4*)&vv[4 * u] = *(float4*)&Ct[r * 34 + seg + 4 * u];
            #pragma unroll
            for (int u = 0; u < 4; ++u) {
                float4 bb = *(const float4*)&bias[cg + 4 * u];
                vv[4 * u + 0] += bb.x; vv[4 * u + 1] += bb.y;
                vv[4 * u + 2] += bb.z; vv[4 * u + 3] += bb.w;
            }
            if (doRot && cg < DROT) {
                int s = rg & (S_ - 1);
                float cs[16], sn[16];
                #pragma unroll
                for (int u = 0; u < 4; ++u) {
                    *(float4*)&cs[4 * u] = *(const float4*)&cosT[s * 256 + cg + 4 * u];
                    *(float4*)&sn[4 * u] = *(const float4*)&sinT[s * 256 + cg + 4 * u];
                }
                #pragma unroll
                for (int j = 0; j < 16; j += 2) {
                    float x1 = vv[j], x2 = vv[j + 1];
                    vv[j]     = x1 * cs[j]     - x2 * sn[j];
                    vv[j + 1] = x2 * cs[j + 1] + x1 * sn[j + 1];
                }
            }
            bf16x8 o0, o1;
            #pragma unroll
            for (int j = 0; j < 8; ++j) { o0[j] = f2bf(vv[j]); o1[j] = f2bf(vv[8 + j]); }
            *(bf16x8*)&Out[(size_t)rg * DATT + cg]     = o0;
            *(bf16x8*)&Out[(size_t)rg * DATT + cg + 8] = o1;
        }
        __syncthreads();
    }
}

// ---- K1b: Vb[2048][512] -> Vt[512][2048] bf16, per batch ----
__global__ __launch_bounds__(256) void k_vt(
    const short* __restrict__ Vb, short* __restrict__ Vt)
{
    int b = blockIdx.z;
    int d0 = blockIdx.x * 64;
    int r0 = blockIdx.y * 64;
    const short* Vp = Vb + (size_t)b * S_ * DATT;
    short* Tp = Vt + (size_t)b * DATT * S_;
    __shared__ short tile[64 * 66];
    int t = threadIdx.x;
    #pragma unroll
    for (int i = 0; i < 2; ++i) {
        int slot = t + 256 * i;
        int row = slot >> 3;
        int c8  = (slot & 7) * 8;
        bf16x8 v = *(const bf16x8*)&Vp[(size_t)(r0 + row) * DATT + d0 + c8];
        #pragma unroll
        for (int j = 0; j < 8; ++j) tile[row * 66 + c8 + j] = v[j];
    }
    __syncthreads();
    int dr = t >> 2, rq = (t & 3) * 16;
    bf16x8 o0, o1;
    #pragma unroll
    for (int j = 0; j < 8; ++j) o0[j] = tile[(rq + j) * 66 + dr];
    #pragma unroll
    for (int j = 0; j < 8; ++j) o1[j] = tile[(rq + 8 + j) * 66 + dr];
    *(bf16x8*)&Tp[(size_t)(d0 + dr) * S_ + r0 + rq]     = o0;
    *(bf16x8*)&Tp[(size_t)(d0 + dr) * S_ + r0 + rq + 8] = o1;
}

// ---- K2a: scores = Q @ K^T * scale -> fp16 raw; BK=64 + swizzle ----
__global__ __launch_bounds__(256) void k_scores_h(
    const short* __restrict__ Qb, const short* __restrict__ Kb,
    unsigned short* __restrict__ Sraw)
{
    __shared__ __align__(16) float smem[8192];     // 32768 B
    short* As = (short*)smem;                      // 128*64 = 16384 B
    short* Bs = (short*)(smem + 4096);             // 16384 B
    float* Ct = smem;                              // 17408 B
    int t = threadIdx.x;
    int l = t & 63, w = t >> 6;
    int wr = (w >> 1) * 64, wc = (w & 1) * 64;
    int fr = l & 15, fk8 = (l >> 4) * 8;
    int xr = (fr & 7) << 3;
    int b = blockIdx.z;
    int iBase = blockIdx.y * 128;
    int jBase = blockIdx.x * 128;
    const short* Qp = Qb + (size_t)b * S_ * DATT;
    const short* Kp = Kb + (size_t)b * S_ * DATT;

    f32x4 acc[4][4] = {};
    int srow = w * 8 + (l >> 3);
    int skolsw = (((l & 7) ^ (l >> 3)) * 8);

    for (int k0 = 0; k0 < DATT; k0 += 64) {
        #pragma unroll
        for (int it = 0; it < 4; ++it) {
            int r = it * 32 + srow;
            __builtin_amdgcn_global_load_lds(
                (const __attribute__((address_space(1))) void*)
                    &Qp[(size_t)(iBase + r) * DATT + k0 + skolsw],
                (__attribute__((address_space(3))) void*)
                    &As[(it * 32 + w * 8) * 64],
                16, 0, 0);
            __builtin_amdgcn_global_load_lds(
                (const __attribute__((address_space(1))) void*)
                    &Kp[(size_t)(jBase + r) * DATT + k0 + skolsw],
                (__attribute__((address_space(3))) void*)
                    &Bs[(it * 32 + w * 8) * 64],
                16, 0, 0);
        }
        __syncthreads();
        #pragma unroll
        for (int kk = 0; kk < 64; kk += 32) {
            bf16x8 af[4], bfr[4];
            #pragma unroll
            for (int m = 0; m < 4; ++m)
                af[m] = *(const bf16x8*)&As[(wr + m * 16 + fr) * 64 + ((kk + fk8) ^ xr)];
            #pragma unroll
            for (int n = 0; n < 4; ++n)
                bfr[n] = *(const bf16x8*)&Bs[(wc + n * 16 + fr) * 64 + ((kk + fk8) ^ xr)];
            #pragma unroll
            for (int m = 0; m < 4; ++m)
                #pragma unroll
                for (int n = 0; n < 4; ++n)
                    acc[m][n] = __builtin_amdgcn_mfma_f32_16x16x32_bf16(af[m], bfr[n], acc[m][n], 0, 0, 0);
        }
        __syncthreads();
    }

    const float scale = 0.04419417382415922f;   // 1/sqrt(512)
    for (int ch = 0; ch < 4; ++ch) {
        if ((w & 1) == (ch >> 1)) {
            int nb = (ch & 1) * 2;
            #pragma unroll
            for (int n2 = 0; n2 < 2; ++n2)
                #pragma unroll
                for (int m = 0; m < 4; ++m)
                    #pragma unroll
                    for (int q = 0; q < 4; ++q)
                        Ct[(wr + m * 16 + (l >> 4) * 4 + q) * 34 + n2 * 16 + fr]
                            = acc[m][nb + n2][q] * scale;
        }
        __syncthreads();
        {
            int r = t >> 1, seg = (t & 1) * 16;
            size_t base = ((size_t)b * S_ + iBase + r) * S_ + jBase + ch * 32 + seg;
            float vv[16];
            #pragma unroll
            for (int u = 0; u < 4; ++u)
                *(float4*)&vv[4 * u] = *(float4*)&Ct[r * 34 + seg + 4 * u];
            u16x8 h0, h1;
            #pragma unroll
            for (int j = 0; j < 8; ++j) { h0[j] = f2h(vv[j]); h1[j] = f2h(vv[8 + j]); }
            *(u16x8*)&Sraw[base]     = h0;
            *(u16x8*)&Sraw[base + 8] = h1;
        }
        __syncthreads();
    }
}

// ---- K3a: softmax: fp16 raw + mask -> fp32 weights + bf16 Pb (in place) ----
__global__ __launch_bounds__(256) void k_softmax_h(
    unsigned short* __restrict__ SrawPb, const int* __restrict__ mask,
    float* __restrict__ wts)
{
    size_t row = blockIdx.x;
    unsigned short* sp = SrawPb + row * S_;
    const int* mp = mask + row * S_;
    float* wp = wts + row * S_;
    int t = threadIdx.x, l = t & 63, w = t >> 6;

    u16x8 raw = *(const u16x8*)&sp[8 * t];
    int4 m0 = *(const int4*)&mp[8 * t];
    int4 m1 = *(const int4*)&mp[8 * t + 4];
    float v[8];
    v[0] = (m0.x == 0) ? -1e-9f : h2f(raw[0]);
    v[1] = (m0.y == 0) ? -1e-9f : h2f(raw[1]);
    v[2] = (m0.z == 0) ? -1e-9f : h2f(raw[2]);
    v[3] = (m0.w == 0) ? -1e-9f : h2f(raw[3]);
    v[4] = (m1.x == 0) ? -1e-9f : h2f(raw[4]);
    v[5] = (m1.y == 0) ? -1e-9f : h2f(raw[5]);
    v[6] = (m1.z == 0) ? -1e-9f : h2f(raw[6]);
    v[7] = (m1.w == 0) ? -1e-9f : h2f(raw[7]);

    float mx = v[0];
    #pragma unroll
    for (int j = 1; j < 8; ++j) mx = fmaxf(mx, v[j]);
    for (int off = 32; off; off >>= 1) mx = fmaxf(mx, __shfl_xor(mx, off));
    __shared__ float red[8];
    if (l == 0) red[w] = mx;
    __syncthreads();
    mx = fmaxf(fmaxf(red[0], red[1]), fmaxf(red[2], red[3]));
    float sum = 0.f;
    #pragma unroll
    for (int j = 0; j < 8; ++j) { v[j] = expf(v[j] - mx); sum += v[j]; }
    for (int off = 32; off; off >>= 1) sum += __shfl_xor(sum, off);
    if (l == 0) red[4 + w] = sum;
    __syncthreads();
    sum = red[4] + red[5] + red[6] + red[7];
    float inv = 1.0f / sum;
    #pragma unroll
    for (int j = 0; j < 8; ++j) v[j] *= inv;

    *(float4*)&wp[8 * t]     = make_float4(v[0], v[1], v[2], v[3]);
    *(float4*)&wp[8 * t + 4] = make_float4(v[4], v[5], v[6], v[7]);
    bf16x8 pb8;
    #pragma unroll
    for (int j = 0; j < 8; ++j) pb8[j] = f2bf(v[j]);
    *(bf16x8*)&sp[8 * t] = pb8;   // Pb overwrites Sraw in place
}

// ---- K4a: context = Pb(bf16) @ Vt^T; BK=64 + swizzle ----
__global__ __launch_bounds__(256) void k_ctx_bf16(
    const short* __restrict__ Pb, const short* __restrict__ Vt,
    float* __restrict__ ctx)
{
    __shared__ __align__(16) float smem[8192];
    short* As = (short*)smem;
    short* Bs = (short*)(smem + 4096);
    float* Ct = smem;
    int t = threadIdx.x;
    int l = t & 63, w = t >> 6;
    int wr = (w >> 1) * 64, wc = (w & 1) * 64;
    int fr = l & 15, fk8 = (l >> 4) * 8;
    int xr = (fr & 7) << 3;
    int b = blockIdx.z;
    int iBase = blockIdx.y * 128;
    int nBase = blockIdx.x * 128;
    const short* Ap = Pb + (size_t)b * S_ * S_;
    const short* Bp = Vt + (size_t)b * DATT * S_;

    f32x4 acc[4][4] = {};
    int srow = w * 8 + (l >> 3);
    int skolsw = (((l & 7) ^ (l >> 3)) * 8);

    for (int k0 = 0; k0 < S_; k0 += 64) {
        #pragma unroll
        for (int it = 0; it < 4; ++it) {
            int r = it * 32 + srow;
            __builtin_amdgcn_global_load_lds(
                (const __attribute__((address_space(1))) void*)
                    &Ap[(size_t)(iBase + r) * S_ + k0 + skolsw],
                (__attribute__((address_space(3))) void*)
                    &As[(it * 32 + w * 8) * 64],
                16, 0, 0);
            __builtin_amdgcn_global_load_lds(
                (const __attribute__((address_space(1))) void*)
                    &Bp[(size_t)(nBase + r) * S_ + k0 + skolsw],
                (__attribute__((address_space(3))) void*)
                    &Bs[(it * 32 + w * 8) * 64],
                16, 0, 0);
        }
        __syncthreads();
        #pragma unroll
        for (int kk = 0; kk < 64; kk += 32) {
            bf16x8 af[4], bfr[4];
            #pragma unroll
            for (int m = 0; m < 4; ++m)
                af[m] = *(const bf16x8*)&As[(wr + m * 16 + fr) * 64 + ((kk + fk8) ^ xr)];
            #pragma unroll
            for (int n = 0; n < 4; ++n)
                bfr[n] = *(const bf16x8*)&Bs[(wc + n * 16 + fr) * 64 + ((kk + fk8) ^ xr)];
            #pragma unroll
            for (int m = 0; m < 4; ++m)
                #pragma unroll
                for (int n = 0; n < 4; ++n)
                    acc[m][n] = __builtin_amdgcn_mfma_f32_16x16x32_bf16(af[m], bfr[n], acc[m][n], 0, 0, 0);
        }
        __syncthreads();
    }

    for (int ch = 0; ch < 4; ++ch) {
        if ((w & 1) == (ch >> 1)) {
            int nb = (ch & 1) * 2;
            #pragma unroll
            for (int n2 = 0; n2 < 2; ++n2)
                #pragma unroll
                for (int m = 0; m < 4; ++m)
                    #pragma unroll
                    for (int q = 0; q < 4; ++q)
                        Ct[(wr + m * 16 + (l >> 4) * 4 + q) * 34 + n2 * 16 + fr]
                            = acc[m][nb + n2][q];
        }
        __syncthreads();
        {
            int r = t >> 1, seg = (t & 1) * 16;
            int gi = iBase + r;
            size_t base = ((size_t)b * S_ + gi) * DATT + nBase + ch * 32 + seg;
            #pragma unroll
            for (int u = 0; u < 4; ++u) {
                float4 vv = *(float4*)&Ct[r * 34 + seg + 4 * u];
                *(float4*)&ctx[base + 4 * u] = vv;
            }
        }
        __syncthreads();
    }
}

// ================= fallback path (small ws), BK=32 legacy =========
__global__ __launch_bounds__(256) void k_scores_f32(
    const short* __restrict__ Qb, const short* __restrict__ Kb,
    const int* __restrict__ mask, float* __restrict__ wOut)
{
    __shared__ __align__(16) float smem[4352];
    short* As = (short*)smem;
    short* Bs = (short*)(smem + 2048);
    float* Ct = smem;
    int t = threadIdx.x;
    int l = t & 63, w = t >> 6;
    int wr = (w >> 1) * 64, wc = (w & 1) * 64;
    int fr = l & 15, fk = (l >> 4) * 8;
    int b = blockIdx.z;
    int iBase = blockIdx.y * 128;
    int jBase = blockIdx.x * 128;
    const short* Qp = Qb + (size_t)b * S_ * DATT;
    const short* Kp = Kb + (size_t)b * S_ * DATT;

    f32x4 acc[4][4] = {};
    int srow = w * 16 + (l >> 2);
    int skol = (l & 3) * 8;

    for (int k0 = 0; k0 < DATT; k0 += 32) {
        #pragma unroll
        for (int it = 0; it < 2; ++it) {
            int r = it * 64 + srow;
            __builtin_amdgcn_global_load_lds(
                (const __attribute__((address_space(1))) void*)
                    &Qp[(size_t)(iBase + r) * DATT + k0 + skol],
                (__attribute__((address_space(3))) void*)
                    &As[(it * 64 + w * 16) * 32],
                16, 0, 0);
            __builtin_amdgcn_global_load_lds(
                (const __attribute__((address_space(1))) void*)
                    &Kp[(size_t)(jBase + r) * DATT + k0 + skol],
                (__attribute__((address_space(3))) void*)
                    &Bs[(it * 64 + w * 16) * 32],
                16, 0, 0);
        }
        __syncthreads();
        bf16x8 af[4], bfr[4];
        #pragma unroll
        for (int m = 0; m < 4; ++m)
            af[m] = *(const bf16x8*)&As[(wr + m * 16 + fr) * 32 + fk];
        #pragma unroll
        for (int n = 0; n < 4; ++n)
            bfr[n] = *(const bf16x8*)&Bs[(wc + n * 16 + fr) * 32 + fk];
        #pragma unroll
        for (int m = 0; m < 4; ++m)
            #pragma unroll
            for (int n = 0; n < 4; ++n)
                acc[m][n] = __builtin_amdgcn_mfma_f32_16x16x32_bf16(af[m], bfr[n], acc[m][n], 0, 0, 0);
        __syncthreads();
    }

    const float scale = 0.04419417382415922f;
    for (int ch = 0; ch < 4; ++ch) {
        if ((w & 1) == (ch >> 1)) {
            int nb = (ch & 1) * 2;
            #pragma unroll
            for (int n2 = 0; n2 < 2; ++n2)
                #pragma unroll
                for (int m = 0; m < 4; ++m)
                    #pragma unroll
                    for (int q = 0; q < 4; ++q)
                        Ct[(wr + m * 16 + (l >> 4) * 4 + q) * 34 + n2 * 16 + fr]
                            = acc[m][nb + n2][q] * scale;
        }
        __syncthreads();
        {
            int r = t >> 1, seg = (t & 1) * 16;
            size_t base = ((size_t)b * S_ + iBase + r) * S_ + jBase + ch * 32 + seg;
            #pragma unroll
            for (int u = 0; u < 4; ++u) {
                float4 vv = *(float4*)&Ct[r * 34 + seg + 4 * u];
                int4  mm = *(const int4*)&mask[base + 4 * u];
                vv.x = (mm.x == 0) ? -1e-9f : vv.x;
                vv.y = (mm.y == 0) ? -1e-9f : vv.y;
                vv.z = (mm.z == 0) ? -1e-9f : vv.z;
                vv.w = (mm.w == 0) ? -1e-9f : vv.w;
                *(float4*)&wOut[base + 4 * u] = vv;
            }
        }
        __syncthreads();
    }
}

__global__ __launch_bounds__(256) void k_softmax_f32(float* __restrict__ wts) {
    size_t row = blockIdx.x;
    float* p = wts + row * S_;
    int t = threadIdx.x, l = t & 63, w = t >> 6;
    float v[8];
    *(float4*)&v[0] = ((const float4*)p)[t];
    *(float4*)&v[4] = ((const float4*)p)[t + 256];
    float mx = v[0];
    #pragma unroll
    for (int j = 1; j < 8; ++j) mx = fmaxf(mx, v[j]);
    for (int off = 32; off; off >>= 1) mx = fmaxf(mx, __shfl_xor(mx, off));
    __shared__ float red[8];
    if (l == 0) red[w] = mx;
    __syncthreads();
    mx = fmaxf(fmaxf(red[0], red[1]), fmaxf(red[2], red[3]));
    float sum = 0.f;
    #pragma unroll
    for (int j = 0; j < 8; ++j) { v[j] = expf(v[j] - mx); sum += v[j]; }
    for (int off = 32; off; off >>= 1) sum += __shfl_xor(sum, off);
    if (l == 0) red[4 + w] = sum;
    __syncthreads();
    sum = red[4] + red[5] + red[6] + red[7];
    float inv = 1.0f / sum;
    #pragma unroll
    for (int j = 0; j < 8; ++j) v[j] *= inv;
    ((float4*)p)[t]       = *(float4*)&v[0];
    ((float4*)p)[t + 256] = *(float4*)&v[4];
}

__global__ __launch_bounds__(256) void k_ctx_f32(
    const float* __restrict__ wts, const short* __restrict__ Vt,
    float* __restrict__ ctx)
{
    __shared__ short As[128 * 40];
    __shared__ short Bs[128 * 32];
    int t = threadIdx.x;
    int l = t & 63, w = t >> 6;
    int wr = (w >> 1) * 64, wc = (w & 1) * 64;
    int fr = l & 15, fk = (l >> 4) * 8;
    int b = blockIdx.z;
    int iBase = blockIdx.y * 128;
    int nBase = blockIdx.x * 128;
    const float* Wp = wts + (size_t)b * S_ * S_;
    const short* Bp = Vt + (size_t)b * DATT * S_;

    f32x4 acc[4][4] = {};
    int trA = t >> 3, tcA = (t & 7) * 4;
    int srow = w * 16 + (l >> 2), skol = (l & 3) * 8;

    for (int k0 = 0; k0 < S_; k0 += 32) {
        #pragma unroll
        for (int it = 0; it < 2; ++it) {
            int r = it * 64 + srow;
            __builtin_amdgcn_global_load_lds(
                (const __attribute__((address_space(1))) void*)
                    &Bp[(size_t)(nBase + r) * S_ + k0 + skol],
                (__attribute__((address_space(3))) void*)
                    &Bs[(it * 64 + w * 16) * 32],
                16, 0, 0);
        }
        #pragma unroll
        for (int ii = 0; ii < 4; ++ii) {
            int r = trA + 32 * ii;
            float4 v = *(const float4*)&Wp[(size_t)(iBase + r) * S_ + k0 + tcA];
            short4 s4 = make_short4(f2bf(v.x), f2bf(v.y), f2bf(v.z), f2bf(v.w));
            *(short4*)&As[r * 40 + tcA] = s4;
        }
        __syncthreads();
        bf16x8 af[4], bfr[4];
        #pragma unroll
        for (int m = 0; m < 4; ++m)
            af[m] = *(const bf16x8*)&As[(wr + m * 16 + fr) * 40 + fk];
        #pragma unroll
        for (int n = 0; n < 4; ++n)
            bfr[n] = *(const bf16x8*)&Bs[(wc + n * 16 + fr) * 32 + fk];
        #pragma unroll
        for (int m = 0; m < 4; ++m)
            #pragma unroll
            for (int n = 0; n < 4; ++n)
                acc[m][n] = __builtin_amdgcn_mfma_f32_16x16x32_bf16(af[m], bfr[n], acc[m][n], 0, 0, 0);
        __syncthreads();
    }

    for (int m = 0; m < 4; ++m) {
        for (int q = 0; q < 4; ++q) {
            int i = iBase + wr + m * 16 + (l >> 4) * 4 + q;
            for (int n = 0; n < 4; ++n) {
                int d = nBase + wc + n * 16 + fr;
                ctx[((size_t)b * S_ + i) * DATT + d] = acc[m][n][q];
            }
        }
    }
}

extern "C" void kernel_launch(void* const* d_in, const int* in_sizes, int n_in,
                              void* d_out, int out_size, void* d_ws, size_t ws_size,
                              hipStream_t stream) {
    const float* query = (const float*)d_in[0];
    const float* key   = (const float*)d_in[1];
    const float* value = (const float*)d_in[2];
    const int*   mask  = (const int*)d_in[3];
    const float* Wq = (const float*)d_in[4];
    const float* bq = (const float*)d_in[5];
    const float* Wk = (const float*)d_in[6];
    const float* bk = (const float*)d_in[7];
    const float* Wv = (const float*)d_in[8];
    const float* bv = (const float*)d_in[9];

    float* ctx = (float*)d_out;                    // B*S*DATT fp32
    float* wts = ctx + (size_t)B_ * S_ * DATT;     // B*S*S fp32

    char* ws = (char*)d_ws;
    const size_t SZ_QKV = (size_t)B_ * S_ * DATT * 2;      // 16.78 MB
    const size_t SZ_WT  = (size_t)DATT * DIN * 2;          // 512 KB
    const size_t SZ_TAB = (size_t)S_ * 256 * 4;            // 2 MB
    short* Qb   = (short*)(ws);
    short* Kb   = (short*)(ws + SZ_QKV);
    short* Vt   = (short*)(ws + 2 * SZ_QKV);
    short* WtQ  = (short*)(ws + 3 * SZ_QKV);
    float* cosT = (float*)(ws + 3 * SZ_QKV + 3 * SZ_WT);
    float* sinT = (float*)(ws + 3 * SZ_QKV + 3 * SZ_WT + SZ_TAB);
    char*  big  = ws + 3 * SZ_QKV + 3 * SZ_WT + 2 * SZ_TAB;
    short* Vb   = (short*)big;                 // dead after k_vt
    unsigned short* Sraw = (unsigned short*)big;  // fp16 raw -> bf16 Pb in place
    const size_t needA = 3 * SZ_QKV + 3 * SZ_WT + 2 * SZ_TAB
                       + (size_t)B_ * S_ * S_ * 2;          // ~123.2 MB
    int useH = ws_size >= needA ? 1 : 0;

    short* WtK = WtQ + (size_t)DATT * DIN;
    short* WtV = WtK + (size_t)DATT * DIN;

    k_tables<<<dim3((S_ * 128) / 256), 256, 0, stream>>>(cosT, sinT);
    k_wt<<<dim3(64, 3), 256, 0, stream>>>(Wq, Wk, Wv, WtQ, WtK, WtV);
    k_proj3<<<dim3(4, 128, 3), 256, 0, stream>>>(query, key, value, WtQ,
                                                 bq, bk, bv, Qb, Kb, Vb,
                                                 cosT, sinT);
    k_vt<<<dim3(8, 32, 8), 256, 0, stream>>>(Vb, Vt);
    if (useH) {
        k_scores_h<<<dim3(16, 16, 8), 256, 0, stream>>>(Qb, Kb, Sraw);
        k_softmax_h<<<dim3(B_ * S_), 256, 0, stream>>>(Sraw, mask, wts);
        k_ctx_bf16<<<dim3(4, 16, 8), 256, 0, stream>>>((short*)Sraw, Vt, ctx);
    } else {
        k_scores_f32<<<dim3(16, 16, 8), 256, 0, stream>>>(Qb, Kb, mask, wts);
        k_softmax_f32<<<dim3(B_ * S_), 256, 0, stream>>>(wts);
        k_ctx_f32<<<dim3(4, 16, 8), 256, 0, stream>>>(wts, Vt, ctx);
    }
}

// Round 11
// 519.683 us; speedup vs baseline: 1.3679x; 1.0088x over previous
//
#include <hip/hip_runtime.h>
#include <hip/hip_bf16.h>
#include <hip/hip_fp16.h>

#define B_   8
#define S_   2048
#define DIN  512
#define DATT 512
#define DROT 256

typedef __attribute__((ext_vector_type(4))) float f32x4;
typedef __attribute__((ext_vector_type(8))) short bf16x8;
typedef __attribute__((ext_vector_type(8))) unsigned short u16x8;

__device__ __forceinline__ short f2bf(float f) {
    __hip_bfloat16 h = __float2bfloat16(f);
    return *reinterpret_cast<short*>(&h);
}
__device__ __forceinline__ unsigned short f2h(float f) {
    __half h = __float2half(f);
    return *reinterpret_cast<unsigned short*>(&h);
}
__device__ __forceinline__ float h2f(unsigned short u) {
    __half h = *reinterpret_cast<__half*>(&u);
    return __half2float(h);
}

// ---- K0: merged prep: rotary tables (bid<1024) + W->Wt bf16 (bid>=1024) ----
__global__ __launch_bounds__(256) void k_prep(
    float* __restrict__ cosT, float* __restrict__ sinT,
    const float* __restrict__ Wq, const float* __restrict__ Wk,
    const float* __restrict__ Wv,
    short* __restrict__ WtQ, short* __restrict__ WtK, short* __restrict__ WtV)
{
    __shared__ float tile[64 * 68];
    int bid = blockIdx.x;
    int t = threadIdx.x;
    if (bid < 1024) {
        int idx = bid * 256 + t;
        int s = idx >> 7;
        int i = idx & 127;
        float e    = (float)(2 * i) / (float)DROT;
        float invf = 1.0f / powf(10000.0f, e);
        float f    = (float)s * invf;
        float c = cosf(f), sn = sinf(f);
        cosT[s * 256 + 2 * i]     = c;
        cosT[s * 256 + 2 * i + 1] = c;
        sinT[s * 256 + 2 * i]     = sn;
        sinT[s * 256 + 2 * i + 1] = sn;
        return;
    }
    int wi = bid - 1024;                 // 0..191
    int mz = wi >> 6;                    // matrix index
    int xi = wi & 63;
    const float* W; short* Wt;
    if (mz == 0)      { W = Wq; Wt = WtQ; }
    else if (mz == 1) { W = Wk; Wt = WtK; }
    else              { W = Wv; Wt = WtV; }
    int kt = xi & 7, nt = xi >> 3;
    int k0 = kt * 64, n0 = nt * 64;
    #pragma unroll
    for (int i = 0; i < 4; ++i) {
        int slot = t + 256 * i;
        int row = slot >> 4;
        int c4  = (slot & 15) * 4;
        float4 v = *(const float4*)&W[(size_t)(k0 + row) * DATT + n0 + c4];
        *(float4*)&tile[row * 68 + c4] = v;
    }
    __syncthreads();
    int nr = t >> 2, kq = (t & 3) * 16;
    bf16x8 o0, o1;
    #pragma unroll
    for (int j = 0; j < 8; ++j) o0[j] = f2bf(tile[(kq + j) * 68 + nr]);
    #pragma unroll
    for (int j = 0; j < 8; ++j) o1[j] = f2bf(tile[(kq + 8 + j) * 68 + nr]);
    *(bf16x8*)&Wt[(size_t)(n0 + nr) * DIN + k0 + kq]     = o0;
    *(bf16x8*)&Wt[(size_t)(n0 + nr) * DIN + k0 + kq + 8] = o1;
}

// ---- K1: merged QKV projection, BK=64, swizzled B staging, XCD swizzle ----
__global__ __launch_bounds__(256) void k_proj3(
    const float* __restrict__ Xq, const float* __restrict__ Xk,
    const float* __restrict__ Xv, const short* __restrict__ Wt0,
    const float* __restrict__ bq, const float* __restrict__ bk,
    const float* __restrict__ bv,
    short* __restrict__ Qb, short* __restrict__ Kb, short* __restrict__ Vb,
    const float* __restrict__ cosT, const float* __restrict__ sinT)
{
    // bijective XCD swizzle: grid (4,128,3) = 1536, q = 192
    int fid = blockIdx.x + 4 * (blockIdx.y + 128 * blockIdx.z);
    fid = (fid & 7) * 192 + (fid >> 3);
    int bx = fid & 3;
    int rem = fid >> 2;
    int by = rem & 127;
    int z  = rem >> 7;

    const float* X    = (z == 0) ? Xq : (z == 1) ? Xk : Xv;
    const float* bias = (z == 0) ? bq : (z == 1) ? bk : bv;
    short*       Out  = (z == 0) ? Qb : (z == 1) ? Kb : Vb;
    const short* Wt   = Wt0 + (size_t)z * DATT * DIN;
    int doRot = (z < 2);

    __shared__ __align__(16) float smem[8704];     // 34816 B
    short* As = (short*)smem;                      // 128*72 shorts
    short* Bs = (short*)(smem + 4608);             // 128*64 shorts
    float* Ct = smem;                              // 128*34 floats
    int t = threadIdx.x;
    int l = t & 63, w = t >> 6;
    int wr = (w >> 1) * 64, wc = (w & 1) * 64;
    int fr = l & 15, fk8 = (l >> 4) * 8;
    int xr = (fr & 7) << 3;
    int rowBase = by * 128;
    int nBase   = bx * 128;

    f32x4 acc[4][4] = {};
    int trA = t >> 4, tcA = (t & 15) * 4;
    int srow = w * 8 + (l >> 3);
    int skolsw = (((l & 7) ^ (l >> 3)) * 8);

    for (int k0 = 0; k0 < DIN; k0 += 64) {
        #pragma unroll
        for (int it = 0; it < 4; ++it) {
            int r = it * 32 + srow;
            __builtin_amdgcn_global_load_lds(
                (const __attribute__((address_space(1))) void*)
                    &Wt[(size_t)(nBase + r) * DIN + k0 + skolsw],
                (__attribute__((address_space(3))) void*)
                    &Bs[(it * 32 + w * 8) * 64],
                16, 0, 0);
        }
        #pragma unroll
        for (int ii = 0; ii < 8; ++ii) {
            int r = ii * 16 + trA;
            float4 v = *(const float4*)&X[(size_t)(rowBase + r) * DIN + k0 + tcA];
            short4 s4 = make_short4(f2bf(v.x), f2bf(v.y), f2bf(v.z), f2bf(v.w));
            *(short4*)&As[r * 72 + tcA] = s4;
        }
        __syncthreads();
        #pragma unroll
        for (int kk = 0; kk < 64; kk += 32) {
            bf16x8 af[4], bfr[4];
            #pragma unroll
            for (int m = 0; m < 4; ++m)
                af[m] = *(const bf16x8*)&As[(wr + m * 16 + fr) * 72 + kk + fk8];
            #pragma unroll
            for (int n = 0; n < 4; ++n)
                bfr[n] = *(const bf16x8*)&Bs[(wc + n * 16 + fr) * 64 + ((kk + fk8) ^ xr)];
            #pragma unroll
            for (int m = 0; m < 4; ++m)
                #pragma unroll
                for (int n = 0; n < 4; ++n)
                    acc[m][n] = __builtin_amdgcn_mfma_f32_16x16x32_bf16(af[m], bfr[n], acc[m][n], 0, 0, 0);
        }
        __syncthreads();
    }

    for (int ch = 0; ch < 4; ++ch) {
        if ((w & 1) == (ch >> 1)) {
            int nb = (ch & 1) * 2;
            #pragma unroll
            for (int n2 = 0; n2 < 2; ++n2)
                #pragma unroll
                for (int m = 0; m < 4; ++m)
                    #pragma unroll
                    for (int q = 0; q < 4; ++q)
                        Ct[(wr + m * 16 + (l >> 4) * 4 + q) * 34 + n2 * 16 + fr]
                            = acc[m][nb + n2][q];
        }
        __syncthreads();
        {
            int r = t >> 1, seg = (t & 1) * 16;
            int rg = rowBase + r;
            int cg = nBase + ch * 32 + seg;
            float vv[16];
            #pragma unroll
            for (int u = 0; u < 4; ++u)
                *(float4*)&vv[4 * u] = *(float4*)&Ct[r * 34 + seg + 4 * u];
            #pragma unroll
            for (int u = 0; u < 4; ++u) {
                float4 bb = *(const float4*)&bias[cg + 4 * u];
                vv[4 * u + 0] += bb.x; vv[4 * u + 1] += bb.y;
                vv[4 * u + 2] += bb.z; vv[4 * u + 3] += bb.w;
            }
            if (doRot && cg < DROT) {
                int s = rg & (S_ - 1);
                float cs[16], sn[16];
                #pragma unroll
                for (int u = 0; u < 4; ++u) {
                    *(float4*)&cs[4 * u] = *(const float4*)&cosT[s * 256 + cg + 4 * u];
                    *(float4*)&sn[4 * u] = *(const float4*)&sinT[s * 256 + cg + 4 * u];
                }
                #pragma unroll
                for (int j = 0; j < 16; j += 2) {
                    float x1 = vv[j], x2 = vv[j + 1];
                    vv[j]     = x1 * cs[j]     - x2 * sn[j];
                    vv[j + 1] = x2 * cs[j + 1] + x1 * sn[j + 1];
                }
            }
            bf16x8 o0, o1;
            #pragma unroll
            for (int j = 0; j < 8; ++j) { o0[j] = f2bf(vv[j]); o1[j] = f2bf(vv[8 + j]); }
            *(bf16x8*)&Out[(size_t)rg * DATT + cg]     = o0;
            *(bf16x8*)&Out[(size_t)rg * DATT + cg + 8] = o1;
        }
        __syncthreads();
    }
}

// ---- K1b: Vb[2048][512] -> Vt[512][2048] bf16, per batch ----
__global__ __launch_bounds__(256) void k_vt(
    const short* __restrict__ Vb, short* __restrict__ Vt)
{
    int b = blockIdx.z;
    int d0 = blockIdx.x * 64;
    int r0 = blockIdx.y * 64;
    const short* Vp = Vb + (size_t)b * S_ * DATT;
    short* Tp = Vt + (size_t)b * DATT * S_;
    __shared__ short tile[64 * 66];
    int t = threadIdx.x;
    #pragma unroll
    for (int i = 0; i < 2; ++i) {
        int slot = t + 256 * i;
        int row = slot >> 3;
        int c8  = (slot & 7) * 8;
        bf16x8 v = *(const bf16x8*)&Vp[(size_t)(r0 + row) * DATT + d0 + c8];
        #pragma unroll
        for (int j = 0; j < 8; ++j) tile[row * 66 + c8 + j] = v[j];
    }
    __syncthreads();
    int dr = t >> 2, rq = (t & 3) * 16;
    bf16x8 o0, o1;
    #pragma unroll
    for (int j = 0; j < 8; ++j) o0[j] = tile[(rq + j) * 66 + dr];
    #pragma unroll
    for (int j = 0; j < 8; ++j) o1[j] = tile[(rq + 8 + j) * 66 + dr];
    *(bf16x8*)&Tp[(size_t)(d0 + dr) * S_ + r0 + rq]     = o0;
    *(bf16x8*)&Tp[(size_t)(d0 + dr) * S_ + r0 + rq + 8] = o1;
}

// ---- K2a: scores = Q @ K^T * scale -> fp16 raw; BK=64 + swizzle + XCD ----
__global__ __launch_bounds__(256) void k_scores_h(
    const short* __restrict__ Qb, const short* __restrict__ Kb,
    unsigned short* __restrict__ Sraw)
{
    // bijective XCD swizzle: grid (16,16,8) = 2048, q = 256 (one batch per XCD)
    int fid = blockIdx.x + 16 * (blockIdx.y + 16 * blockIdx.z);
    fid = (fid & 7) * 256 + (fid >> 3);
    int bxs = fid & 15;
    int rem = fid >> 4;
    int bys = rem & 15;
    int b   = rem >> 4;

    __shared__ __align__(16) float smem[8192];
    short* As = (short*)smem;
    short* Bs = (short*)(smem + 4096);
    float* Ct = smem;
    int t = threadIdx.x;
    int l = t & 63, w = t >> 6;
    int wr = (w >> 1) * 64, wc = (w & 1) * 64;
    int fr = l & 15, fk8 = (l >> 4) * 8;
    int xr = (fr & 7) << 3;
    int iBase = bys * 128;
    int jBase = bxs * 128;
    const short* Qp = Qb + (size_t)b * S_ * DATT;
    const short* Kp = Kb + (size_t)b * S_ * DATT;

    f32x4 acc[4][4] = {};
    int srow = w * 8 + (l >> 3);
    int skolsw = (((l & 7) ^ (l >> 3)) * 8);

    for (int k0 = 0; k0 < DATT; k0 += 64) {
        #pragma unroll
        for (int it = 0; it < 4; ++it) {
            int r = it * 32 + srow;
            __builtin_amdgcn_global_load_lds(
                (const __attribute__((address_space(1))) void*)
                    &Qp[(size_t)(iBase + r) * DATT + k0 + skolsw],
                (__attribute__((address_space(3))) void*)
                    &As[(it * 32 + w * 8) * 64],
                16, 0, 0);
            __builtin_amdgcn_global_load_lds(
                (const __attribute__((address_space(1))) void*)
                    &Kp[(size_t)(jBase + r) * DATT + k0 + skolsw],
                (__attribute__((address_space(3))) void*)
                    &Bs[(it * 32 + w * 8) * 64],
                16, 0, 0);
        }
        __syncthreads();
        #pragma unroll
        for (int kk = 0; kk < 64; kk += 32) {
            bf16x8 af[4], bfr[4];
            #pragma unroll
            for (int m = 0; m < 4; ++m)
                af[m] = *(const bf16x8*)&As[(wr + m * 16 + fr) * 64 + ((kk + fk8) ^ xr)];
            #pragma unroll
            for (int n = 0; n < 4; ++n)
                bfr[n] = *(const bf16x8*)&Bs[(wc + n * 16 + fr) * 64 + ((kk + fk8) ^ xr)];
            #pragma unroll
            for (int m = 0; m < 4; ++m)
                #pragma unroll
                for (int n = 0; n < 4; ++n)
                    acc[m][n] = __builtin_amdgcn_mfma_f32_16x16x32_bf16(af[m], bfr[n], acc[m][n], 0, 0, 0);
        }
        __syncthreads();
    }

    const float scale = 0.04419417382415922f;   // 1/sqrt(512)
    for (int ch = 0; ch < 4; ++ch) {
        if ((w & 1) == (ch >> 1)) {
            int nb = (ch & 1) * 2;
            #pragma unroll
            for (int n2 = 0; n2 < 2; ++n2)
                #pragma unroll
                for (int m = 0; m < 4; ++m)
                    #pragma unroll
                    for (int q = 0; q < 4; ++q)
                        Ct[(wr + m * 16 + (l >> 4) * 4 + q) * 34 + n2 * 16 + fr]
                            = acc[m][nb + n2][q] * scale;
        }
        __syncthreads();
        {
            int r = t >> 1, seg = (t & 1) * 16;
            size_t base = ((size_t)b * S_ + iBase + r) * S_ + jBase + ch * 32 + seg;
            float vv[16];
            #pragma unroll
            for (int u = 0; u < 4; ++u)
                *(float4*)&vv[4 * u] = *(float4*)&Ct[r * 34 + seg + 4 * u];
            u16x8 h0, h1;
            #pragma unroll
            for (int j = 0; j < 8; ++j) { h0[j] = f2h(vv[j]); h1[j] = f2h(vv[8 + j]); }
            *(u16x8*)&Sraw[base]     = h0;
            *(u16x8*)&Sraw[base + 8] = h1;
        }
        __syncthreads();
    }
}

// ---- K3a: softmax: fp16 raw + mask -> fp32 weights + bf16 Pb (in place) ----
__global__ __launch_bounds__(256) void k_softmax_h(
    unsigned short* __restrict__ SrawPb, const int* __restrict__ mask,
    float* __restrict__ wts)
{
    size_t row = blockIdx.x;
    unsigned short* sp = SrawPb + row * S_;
    const int* mp = mask + row * S_;
    float* wp = wts + row * S_;
    int t = threadIdx.x, l = t & 63, w = t >> 6;

    u16x8 raw = *(const u16x8*)&sp[8 * t];
    int4 m0 = *(const int4*)&mp[8 * t];
    int4 m1 = *(const int4*)&mp[8 * t + 4];
    float v[8];
    v[0] = (m0.x == 0) ? -1e-9f : h2f(raw[0]);
    v[1] = (m0.y == 0) ? -1e-9f : h2f(raw[1]);
    v[2] = (m0.z == 0) ? -1e-9f : h2f(raw[2]);
    v[3] = (m0.w == 0) ? -1e-9f : h2f(raw[3]);
    v[4] = (m1.x == 0) ? -1e-9f : h2f(raw[4]);
    v[5] = (m1.y == 0) ? -1e-9f : h2f(raw[5]);
    v[6] = (m1.z == 0) ? -1e-9f : h2f(raw[6]);
    v[7] = (m1.w == 0) ? -1e-9f : h2f(raw[7]);

    float mx = v[0];
    #pragma unroll
    for (int j = 1; j < 8; ++j) mx = fmaxf(mx, v[j]);
    for (int off = 32; off; off >>= 1) mx = fmaxf(mx, __shfl_xor(mx, off));
    __shared__ float red[8];
    if (l == 0) red[w] = mx;
    __syncthreads();
    mx = fmaxf(fmaxf(red[0], red[1]), fmaxf(red[2], red[3]));
    float sum = 0.f;
    #pragma unroll
    for (int j = 0; j < 8; ++j) { v[j] = expf(v[j] - mx); sum += v[j]; }
    for (int off = 32; off; off >>= 1) sum += __shfl_xor(sum, off);
    if (l == 0) red[4 + w] = sum;
    __syncthreads();
    sum = red[4] + red[5] + red[6] + red[7];
    float inv = 1.0f / sum;
    #pragma unroll
    for (int j = 0; j < 8; ++j) v[j] *= inv;

    *(float4*)&wp[8 * t]     = make_float4(v[0], v[1], v[2], v[3]);
    *(float4*)&wp[8 * t + 4] = make_float4(v[4], v[5], v[6], v[7]);
    bf16x8 pb8;
    #pragma unroll
    for (int j = 0; j < 8; ++j) pb8[j] = f2bf(v[j]);
    *(bf16x8*)&sp[8 * t] = pb8;   // Pb overwrites Sraw in place
}

// ---- K4a: context = Pb(bf16) @ Vt^T; BK=64 + swizzle + XCD ----
__global__ __launch_bounds__(256) void k_ctx_bf16(
    const short* __restrict__ Pb, const short* __restrict__ Vt,
    float* __restrict__ ctx)
{
    // bijective XCD swizzle: grid (4,16,8) = 512, q = 64 (one batch per XCD)
    int fid = blockIdx.x + 4 * (blockIdx.y + 16 * blockIdx.z);
    fid = (fid & 7) * 64 + (fid >> 3);
    int bxs = fid & 3;
    int rem = fid >> 2;
    int bys = rem & 15;
    int b   = rem >> 4;

    __shared__ __align__(16) float smem[8192];
    short* As = (short*)smem;
    short* Bs = (short*)(smem + 4096);
    float* Ct = smem;
    int t = threadIdx.x;
    int l = t & 63, w = t >> 6;
    int wr = (w >> 1) * 64, wc = (w & 1) * 64;
    int fr = l & 15, fk8 = (l >> 4) * 8;
    int xr = (fr & 7) << 3;
    int iBase = bys * 128;
    int nBase = bxs * 128;
    const short* Ap = Pb + (size_t)b * S_ * S_;
    const short* Bp = Vt + (size_t)b * DATT * S_;

    f32x4 acc[4][4] = {};
    int srow = w * 8 + (l >> 3);
    int skolsw = (((l & 7) ^ (l >> 3)) * 8);

    for (int k0 = 0; k0 < S_; k0 += 64) {
        #pragma unroll
        for (int it = 0; it < 4; ++it) {
            int r = it * 32 + srow;
            __builtin_amdgcn_global_load_lds(
                (const __attribute__((address_space(1))) void*)
                    &Ap[(size_t)(iBase + r) * S_ + k0 + skolsw],
                (__attribute__((address_space(3))) void*)
                    &As[(it * 32 + w * 8) * 64],
                16, 0, 0);
            __builtin_amdgcn_global_load_lds(
                (const __attribute__((address_space(1))) void*)
                    &Bp[(size_t)(nBase + r) * S_ + k0 + skolsw],
                (__attribute__((address_space(3))) void*)
                    &Bs[(it * 32 + w * 8) * 64],
                16, 0, 0);
        }
        __syncthreads();
        #pragma unroll
        for (int kk = 0; kk < 64; kk += 32) {
            bf16x8 af[4], bfr[4];
            #pragma unroll
            for (int m = 0; m < 4; ++m)
                af[m] = *(const bf16x8*)&As[(wr + m * 16 + fr) * 64 + ((kk + fk8) ^ xr)];
            #pragma unroll
            for (int n = 0; n < 4; ++n)
                bfr[n] = *(const bf16x8*)&Bs[(wc + n * 16 + fr) * 64 + ((kk + fk8) ^ xr)];
            #pragma unroll
            for (int m = 0; m < 4; ++m)
                #pragma unroll
                for (int n = 0; n < 4; ++n)
                    acc[m][n] = __builtin_amdgcn_mfma_f32_16x16x32_bf16(af[m], bfr[n], acc[m][n], 0, 0, 0);
        }
        __syncthreads();
    }

    for (int ch = 0; ch < 4; ++ch) {
        if ((w & 1) == (ch >> 1)) {
            int nb = (ch & 1) * 2;
            #pragma unroll
            for (int n2 = 0; n2 < 2; ++n2)
                #pragma unroll
                for (int m = 0; m < 4; ++m)
                    #pragma unroll
                    for (int q = 0; q < 4; ++q)
                        Ct[(wr + m * 16 + (l >> 4) * 4 + q) * 34 + n2 * 16 + fr]
                            = acc[m][nb + n2][q];
        }
        __syncthreads();
        {
            int r = t >> 1, seg = (t & 1) * 16;
            int gi = iBase + r;
            size_t base = ((size_t)b * S_ + gi) * DATT + nBase + ch * 32 + seg;
            #pragma unroll
            for (int u = 0; u < 4; ++u) {
                float4 vv = *(float4*)&Ct[r * 34 + seg + 4 * u];
                *(float4*)&ctx[base + 4 * u] = vv;
            }
        }
        __syncthreads();
    }
}

// ================= fallback path (small ws), BK=32 legacy =========
__global__ __launch_bounds__(256) void k_scores_f32(
    const short* __restrict__ Qb, const short* __restrict__ Kb,
    const int* __restrict__ mask, float* __restrict__ wOut)
{
    __shared__ __align__(16) float smem[4352];
    short* As = (short*)smem;
    short* Bs = (short*)(smem + 2048);
    float* Ct = smem;
    int t = threadIdx.x;
    int l = t & 63, w = t >> 6;
    int wr = (w >> 1) * 64, wc = (w & 1) * 64;
    int fr = l & 15, fk = (l >> 4) * 8;
    int b = blockIdx.z;
    int iBase = blockIdx.y * 128;
    int jBase = blockIdx.x * 128;
    const short* Qp = Qb + (size_t)b * S_ * DATT;
    const short* Kp = Kb + (size_t)b * S_ * DATT;

    f32x4 acc[4][4] = {};
    int srow = w * 16 + (l >> 2);
    int skol = (l & 3) * 8;

    for (int k0 = 0; k0 < DATT; k0 += 32) {
        #pragma unroll
        for (int it = 0; it < 2; ++it) {
            int r = it * 64 + srow;
            __builtin_amdgcn_global_load_lds(
                (const __attribute__((address_space(1))) void*)
                    &Qp[(size_t)(iBase + r) * DATT + k0 + skol],
                (__attribute__((address_space(3))) void*)
                    &As[(it * 64 + w * 16) * 32],
                16, 0, 0);
            __builtin_amdgcn_global_load_lds(
                (const __attribute__((address_space(1))) void*)
                    &Kp[(size_t)(jBase + r) * DATT + k0 + skol],
                (__attribute__((address_space(3))) void*)
                    &Bs[(it * 64 + w * 16) * 32],
                16, 0, 0);
        }
        __syncthreads();
        bf16x8 af[4], bfr[4];
        #pragma unroll
        for (int m = 0; m < 4; ++m)
            af[m] = *(const bf16x8*)&As[(wr + m * 16 + fr) * 32 + fk];
        #pragma unroll
        for (int n = 0; n < 4; ++n)
            bfr[n] = *(const bf16x8*)&Bs[(wc + n * 16 + fr) * 32 + fk];
        #pragma unroll
        for (int m = 0; m < 4; ++m)
            #pragma unroll
            for (int n = 0; n < 4; ++n)
                acc[m][n] = __builtin_amdgcn_mfma_f32_16x16x32_bf16(af[m], bfr[n], acc[m][n], 0, 0, 0);
        __syncthreads();
    }

    const float scale = 0.04419417382415922f;
    for (int ch = 0; ch < 4; ++ch) {
        if ((w & 1) == (ch >> 1)) {
            int nb = (ch & 1) * 2;
            #pragma unroll
            for (int n2 = 0; n2 < 2; ++n2)
                #pragma unroll
                for (int m = 0; m < 4; ++m)
                    #pragma unroll
                    for (int q = 0; q < 4; ++q)
                        Ct[(wr + m * 16 + (l >> 4) * 4 + q) * 34 + n2 * 16 + fr]
                            = acc[m][nb + n2][q] * scale;
        }
        __syncthreads();
        {
            int r = t >> 1, seg = (t & 1) * 16;
            size_t base = ((size_t)b * S_ + iBase + r) * S_ + jBase + ch * 32 + seg;
            #pragma unroll
            for (int u = 0; u < 4; ++u) {
                float4 vv = *(float4*)&Ct[r * 34 + seg + 4 * u];
                int4  mm = *(const int4*)&mask[base + 4 * u];
                vv.x = (mm.x == 0) ? -1e-9f : vv.x;
                vv.y = (mm.y == 0) ? -1e-9f : vv.y;
                vv.z = (mm.z == 0) ? -1e-9f : vv.z;
                vv.w = (mm.w == 0) ? -1e-9f : vv.w;
                *(float4*)&wOut[base + 4 * u] = vv;
            }
        }
        __syncthreads();
    }
}

__global__ __launch_bounds__(256) void k_softmax_f32(float* __restrict__ wts) {
    size_t row = blockIdx.x;
    float* p = wts + row * S_;
    int t = threadIdx.x, l = t & 63, w = t >> 6;
    float v[8];
    *(float4*)&v[0] = ((const float4*)p)[t];
    *(float4*)&v[4] = ((const float4*)p)[t + 256];
    float mx = v[0];
    #pragma unroll
    for (int j = 1; j < 8; ++j) mx = fmaxf(mx, v[j]);
    for (int off = 32; off; off >>= 1) mx = fmaxf(mx, __shfl_xor(mx, off));
    __shared__ float red[8];
    if (l == 0) red[w] = mx;
    __syncthreads();
    mx = fmaxf(fmaxf(red[0], red[1]), fmaxf(red[2], red[3]));
    float sum = 0.f;
    #pragma unroll
    for (int j = 0; j < 8; ++j) { v[j] = expf(v[j] - mx); sum += v[j]; }
    for (int off = 32; off; off >>= 1) sum += __shfl_xor(sum, off);
    if (l == 0) red[4 + w] = sum;
    __syncthreads();
    sum = red[4] + red[5] + red[6] + red[7];
    float inv = 1.0f / sum;
    #pragma unroll
    for (int j = 0; j < 8; ++j) v[j] *= inv;
    ((float4*)p)[t]       = *(float4*)&v[0];
    ((float4*)p)[t + 256] = *(float4*)&v[4];
}

__global__ __launch_bounds__(256) void k_ctx_f32(
    const float* __restrict__ wts, const short* __restrict__ Vt,
    float* __restrict__ ctx)
{
    __shared__ short As[128 * 40];
    __shared__ short Bs[128 * 32];
    int t = threadIdx.x;
    int l = t & 63, w = t >> 6;
    int wr = (w >> 1) * 64, wc = (w & 1) * 64;
    int fr = l & 15, fk = (l >> 4) * 8;
    int b = blockIdx.z;
    int iBase = blockIdx.y * 128;
    int nBase = blockIdx.x * 128;
    const float* Wp = wts + (size_t)b * S_ * S_;
    const short* Bp = Vt + (size_t)b * DATT * S_;

    f32x4 acc[4][4] = {};
    int trA = t >> 3, tcA = (t & 7) * 4;
    int srow = w * 16 + (l >> 2), skol = (l & 3) * 8;

    for (int k0 = 0; k0 < S_; k0 += 32) {
        #pragma unroll
        for (int it = 0; it < 2; ++it) {
            int r = it * 64 + srow;
            __builtin_amdgcn_global_load_lds(
                (const __attribute__((address_space(1))) void*)
                    &Bp[(size_t)(nBase + r) * S_ + k0 + skol],
                (__attribute__((address_space(3))) void*)
                    &Bs[(it * 64 + w * 16) * 32],
                16, 0, 0);
        }
        #pragma unroll
        for (int ii = 0; ii < 4; ++ii) {
            int r = trA + 32 * ii;
            float4 v = *(const float4*)&Wp[(size_t)(iBase + r) * S_ + k0 + tcA];
            short4 s4 = make_short4(f2bf(v.x), f2bf(v.y), f2bf(v.z), f2bf(v.w));
            *(short4*)&As[r * 40 + tcA] = s4;
        }
        __syncthreads();
        bf16x8 af[4], bfr[4];
        #pragma unroll
        for (int m = 0; m < 4; ++m)
            af[m] = *(const bf16x8*)&As[(wr + m * 16 + fr) * 40 + fk];
        #pragma unroll
        for (int n = 0; n < 4; ++n)
            bfr[n] = *(const bf16x8*)&Bs[(wc + n * 16 + fr) * 32 + fk];
        #pragma unroll
        for (int m = 0; m < 4; ++m)
            #pragma unroll
            for (int n = 0; n < 4; ++n)
                acc[m][n] = __builtin_amdgcn_mfma_f32_16x16x32_bf16(af[m], bfr[n], acc[m][n], 0, 0, 0);
        __syncthreads();
    }

    for (int m = 0; m < 4; ++m) {
        for (int q = 0; q < 4; ++q) {
            int i = iBase + wr + m * 16 + (l >> 4) * 4 + q;
            for (int n = 0; n < 4; ++n) {
                int d = nBase + wc + n * 16 + fr;
                ctx[((size_t)b * S_ + i) * DATT + d] = acc[m][n][q];
            }
        }
    }
}

extern "C" void kernel_launch(void* const* d_in, const int* in_sizes, int n_in,
                              void* d_out, int out_size, void* d_ws, size_t ws_size,
                              hipStream_t stream) {
    const float* query = (const float*)d_in[0];
    const float* key   = (const float*)d_in[1];
    const float* value = (const float*)d_in[2];
    const int*   mask  = (const int*)d_in[3];
    const float* Wq = (const float*)d_in[4];
    const float* bq = (const float*)d_in[5];
    const float* Wk = (const float*)d_in[6];
    const float* bk = (const float*)d_in[7];
    const float* Wv = (const float*)d_in[8];
    const float* bv = (const float*)d_in[9];

    float* ctx = (float*)d_out;                    // B*S*DATT fp32
    float* wts = ctx + (size_t)B_ * S_ * DATT;     // B*S*S fp32

    char* ws = (char*)d_ws;
    const size_t SZ_QKV = (size_t)B_ * S_ * DATT * 2;      // 16.78 MB
    const size_t SZ_WT  = (size_t)DATT * DIN * 2;          // 512 KB
    const size_t SZ_TAB = (size_t)S_ * 256 * 4;            // 2 MB
    short* Qb   = (short*)(ws);
    short* Kb   = (short*)(ws + SZ_QKV);
    short* Vt   = (short*)(ws + 2 * SZ_QKV);
    short* WtQ  = (short*)(ws + 3 * SZ_QKV);
    float* cosT = (float*)(ws + 3 * SZ_QKV + 3 * SZ_WT);
    float* sinT = (float*)(ws + 3 * SZ_QKV + 3 * SZ_WT + SZ_TAB);
    char*  big  = ws + 3 * SZ_QKV + 3 * SZ_WT + 2 * SZ_TAB;
    short* Vb   = (short*)big;                 // dead after k_vt
    unsigned short* Sraw = (unsigned short*)big;  // fp16 raw -> bf16 Pb in place
    const size_t needA = 3 * SZ_QKV + 3 * SZ_WT + 2 * SZ_TAB
                       + (size_t)B_ * S_ * S_ * 2;          // ~123.2 MB
    int useH = ws_size >= needA ? 1 : 0;

    short* WtK = WtQ + (size_t)DATT * DIN;
    short* WtV = WtK + (size_t)DATT * DIN;

    k_prep<<<dim3(1216), 256, 0, stream>>>(cosT, sinT, Wq, Wk, Wv, WtQ, WtK, WtV);
    k_proj3<<<dim3(4, 128, 3), 256, 0, stream>>>(query, key, value, WtQ,
                                                 bq, bk, bv, Qb, Kb, Vb,
                                                 cosT, sinT);
    k_vt<<<dim3(8, 32, 8), 256, 0, stream>>>(Vb, Vt);
    if (useH) {
        k_scores_h<<<dim3(16, 16, 8), 256, 0, stream>>>(Qb, Kb, Sraw);
        k_softmax_h<<<dim3(B_ * S_), 256, 0, stream>>>(Sraw, mask, wts);
        k_ctx_bf16<<<dim3(4, 16, 8), 256, 0, stream>>>((short*)Sraw, Vt, ctx);
    } else {
        k_scores_f32<<<dim3(16, 16, 8), 256, 0, stream>>>(Qb, Kb, mask, wts);
        k_softmax_f32<<<dim3(B_ * S_), 256, 0, stream>>>(wts);
        k_ctx_f32<<<dim3(4, 16, 8), 256, 0, stream>>>(wts, Vt, ctx);
    }
}

// Round 12
// 504.033 us; speedup vs baseline: 1.4104x; 1.0311x over previous
//
#include <hip/hip_runtime.h>
#include <hip/hip_bf16.h>
#include <hip/hip_fp16.h>

#define B_   8
#define S_   2048
#define DIN  512
#define DATT 512
#define DROT 256

typedef __attribute__((ext_vector_type(4))) float f32x4;
typedef __attribute__((ext_vector_type(8))) short bf16x8;
typedef __attribute__((ext_vector_type(8))) unsigned short u16x8;

__device__ __forceinline__ short f2bf(float f) {
    __hip_bfloat16 h = __float2bfloat16(f);
    return *reinterpret_cast<short*>(&h);
}
__device__ __forceinline__ unsigned short f2h(float f) {
    __half h = __float2half(f);
    return *reinterpret_cast<unsigned short*>(&h);
}
__device__ __forceinline__ float h2f(unsigned short u) {
    __half h = *reinterpret_cast<__half*>(&u);
    return __half2float(h);
}

// ---- K0: merged prep: rotary tables (bid<1024) + W->Wt bf16 (bid>=1024) ----
__global__ __launch_bounds__(256) void k_prep(
    float* __restrict__ cosT, float* __restrict__ sinT,
    const float* __restrict__ Wq, const float* __restrict__ Wk,
    const float* __restrict__ Wv,
    short* __restrict__ WtQ, short* __restrict__ WtK, short* __restrict__ WtV)
{
    __shared__ float tile[64 * 68];
    int bid = blockIdx.x;
    int t = threadIdx.x;
    if (bid < 1024) {
        int idx = bid * 256 + t;
        int s = idx >> 7;
        int i = idx & 127;
        float e    = (float)(2 * i) / (float)DROT;
        float invf = 1.0f / powf(10000.0f, e);
        float f    = (float)s * invf;
        float c = cosf(f), sn = sinf(f);
        cosT[s * 256 + 2 * i]     = c;
        cosT[s * 256 + 2 * i + 1] = c;
        sinT[s * 256 + 2 * i]     = sn;
        sinT[s * 256 + 2 * i + 1] = sn;
        return;
    }
    int wi = bid - 1024;
    int mz = wi >> 6;
    int xi = wi & 63;
    const float* W; short* Wt;
    if (mz == 0)      { W = Wq; Wt = WtQ; }
    else if (mz == 1) { W = Wk; Wt = WtK; }
    else              { W = Wv; Wt = WtV; }
    int kt = xi & 7, nt = xi >> 3;
    int k0 = kt * 64, n0 = nt * 64;
    #pragma unroll
    for (int i = 0; i < 4; ++i) {
        int slot = t + 256 * i;
        int row = slot >> 4;
        int c4  = (slot & 15) * 4;
        float4 v = *(const float4*)&W[(size_t)(k0 + row) * DATT + n0 + c4];
        *(float4*)&tile[row * 68 + c4] = v;
    }
    __syncthreads();
    int nr = t >> 2, kq = (t & 3) * 16;
    bf16x8 o0, o1;
    #pragma unroll
    for (int j = 0; j < 8; ++j) o0[j] = f2bf(tile[(kq + j) * 68 + nr]);
    #pragma unroll
    for (int j = 0; j < 8; ++j) o1[j] = f2bf(tile[(kq + 8 + j) * 68 + nr]);
    *(bf16x8*)&Wt[(size_t)(n0 + nr) * DIN + k0 + kq]     = o0;
    *(bf16x8*)&Wt[(size_t)(n0 + nr) * DIN + k0 + kq + 8] = o1;
}

// ---- K1: merged QKV projection; BK=64, dbuf prefetch pipeline ----
__global__ __launch_bounds__(256) void k_proj3(
    const float* __restrict__ Xq, const float* __restrict__ Xk,
    const float* __restrict__ Xv, const short* __restrict__ Wt0,
    const float* __restrict__ bq, const float* __restrict__ bk,
    const float* __restrict__ bv,
    short* __restrict__ Qb, short* __restrict__ Kb, short* __restrict__ Vb,
    const float* __restrict__ cosT, const float* __restrict__ sinT)
{
    int fid = blockIdx.x + 4 * (blockIdx.y + 128 * blockIdx.z);
    fid = (fid & 7) * 192 + (fid >> 3);
    int bx = fid & 3;
    int rem = fid >> 2;
    int by = rem & 127;
    int z  = rem >> 7;

    const float* X    = (z == 0) ? Xq : (z == 1) ? Xk : Xv;
    const float* bias = (z == 0) ? bq : (z == 1) ? bk : bv;
    short*       Out  = (z == 0) ? Qb : (z == 1) ? Kb : Vb;
    const short* Wt   = Wt0 + (size_t)z * DATT * DIN;
    int doRot = (z < 2);

    // LDS: As dbuf 2*18432B + Bs dbuf 2*16384B = 69632 B; Ct aliases front
    __shared__ __align__(16) float smem[17408];
    short* Asb = (short*)smem;              // buf stride 9216 shorts
    short* Bsb = (short*)(smem + 9216);     // buf stride 8192 shorts
    float* Ct  = smem;
    int t = threadIdx.x;
    int l = t & 63, w = t >> 6;
    int wr = (w >> 1) * 64, wc = (w & 1) * 64;
    int fr = l & 15, fk8 = (l >> 4) * 8;
    int xr = (fr & 7) << 3;
    int rowBase = by * 128;
    int nBase   = bx * 128;

    f32x4 acc[4][4] = {};
    int trA = t >> 4, tcA = (t & 15) * 4;
    int srow = w * 8 + (l >> 3);
    int skolsw = (((l & 7) ^ (l >> 3)) * 8);

    float4 xv[8];
    // prologue: tile 0
    #pragma unroll
    for (int ii = 0; ii < 8; ++ii)
        xv[ii] = *(const float4*)&X[(size_t)(rowBase + ii * 16 + trA) * DIN + tcA];
    #pragma unroll
    for (int it = 0; it < 4; ++it) {
        int r = it * 32 + srow;
        __builtin_amdgcn_global_load_lds(
            (const __attribute__((address_space(1))) void*)
                &Wt[(size_t)(nBase + r) * DIN + skolsw],
            (__attribute__((address_space(3))) void*)
                &Bsb[(it * 32 + w * 8) * 64],
            16, 0, 0);
    }
    #pragma unroll
    for (int ii = 0; ii < 8; ++ii) {
        short4 s4 = make_short4(f2bf(xv[ii].x), f2bf(xv[ii].y),
                                f2bf(xv[ii].z), f2bf(xv[ii].w));
        *(short4*)&Asb[(ii * 16 + trA) * 72 + tcA] = s4;
    }
    __syncthreads();

    for (int kt = 0; kt < 8; ++kt) {
        int cur = kt & 1;
        if (kt < 7) {
            int k1 = (kt + 1) * 64;
            #pragma unroll
            for (int ii = 0; ii < 8; ++ii)
                xv[ii] = *(const float4*)&X[(size_t)(rowBase + ii * 16 + trA) * DIN + k1 + tcA];
            short* Bd = Bsb + (cur ^ 1) * 8192;
            #pragma unroll
            for (int it = 0; it < 4; ++it) {
                int r = it * 32 + srow;
                __builtin_amdgcn_global_load_lds(
                    (const __attribute__((address_space(1))) void*)
                        &Wt[(size_t)(nBase + r) * DIN + k1 + skolsw],
                    (__attribute__((address_space(3))) void*)
                        &Bd[(it * 32 + w * 8) * 64],
                    16, 0, 0);
            }
        }
        // compute(cur)
        {
            short* Ac = Asb + cur * 9216;
            short* Bc = Bsb + cur * 8192;
            #pragma unroll
            for (int kk = 0; kk < 64; kk += 32) {
                bf16x8 af[4], bfr[4];
                #pragma unroll
                for (int m = 0; m < 4; ++m)
                    af[m] = *(const bf16x8*)&Ac[(wr + m * 16 + fr) * 72 + kk + fk8];
                #pragma unroll
                for (int n = 0; n < 4; ++n)
                    bfr[n] = *(const bf16x8*)&Bc[(wc + n * 16 + fr) * 64 + ((kk + fk8) ^ xr)];
                #pragma unroll
                for (int m = 0; m < 4; ++m)
                    #pragma unroll
                    for (int n = 0; n < 4; ++n)
                        acc[m][n] = __builtin_amdgcn_mfma_f32_16x16x32_bf16(af[m], bfr[n], acc[m][n], 0, 0, 0);
            }
        }
        if (kt < 7) {
            short* Ad = Asb + (cur ^ 1) * 9216;
            #pragma unroll
            for (int ii = 0; ii < 8; ++ii) {
                short4 s4 = make_short4(f2bf(xv[ii].x), f2bf(xv[ii].y),
                                        f2bf(xv[ii].z), f2bf(xv[ii].w));
                *(short4*)&Ad[(ii * 16 + trA) * 72 + tcA] = s4;
            }
        }
        __syncthreads();
    }

    for (int ch = 0; ch < 4; ++ch) {
        if ((w & 1) == (ch >> 1)) {
            int nb = (ch & 1) * 2;
            #pragma unroll
            for (int n2 = 0; n2 < 2; ++n2)
                #pragma unroll
                for (int m = 0; m < 4; ++m)
                    #pragma unroll
                    for (int q = 0; q < 4; ++q)
                        Ct[(wr + m * 16 + (l >> 4) * 4 + q) * 34 + n2 * 16 + fr]
                            = acc[m][nb + n2][q];
        }
        __syncthreads();
        {
            int r = t >> 1, seg = (t & 1) * 16;
            int rg = rowBase + r;
            int cg = nBase + ch * 32 + seg;
            float vv[16];
            #pragma unroll
            for (int u = 0; u < 4; ++u)
                *(float4*)&vv[4 * u] = *(float4*)&Ct[r * 34 + seg + 4 * u];
            #pragma unroll
            for (int u = 0; u < 4; ++u) {
                float4 bb = *(const float4*)&bias[cg + 4 * u];
                vv[4 * u + 0] += bb.x; vv[4 * u + 1] += bb.y;
                vv[4 * u + 2] += bb.z; vv[4 * u + 3] += bb.w;
            }
            if (doRot && cg < DROT) {
                int s = rg & (S_ - 1);
                float cs[16], sn[16];
                #pragma unroll
                for (int u = 0; u < 4; ++u) {
                    *(float4*)&cs[4 * u] = *(const float4*)&cosT[s * 256 + cg + 4 * u];
                    *(float4*)&sn[4 * u] = *(const float4*)&sinT[s * 256 + cg + 4 * u];
                }
                #pragma unroll
                for (int j = 0; j < 16; j += 2) {
                    float x1 = vv[j], x2 = vv[j + 1];
                    vv[j]     = x1 * cs[j]     - x2 * sn[j];
                    vv[j + 1] = x2 * cs[j + 1] + x1 * sn[j + 1];
                }
            }
            bf16x8 o0, o1;
            #pragma unroll
            for (int j = 0; j < 8; ++j) { o0[j] = f2bf(vv[j]); o1[j] = f2bf(vv[8 + j]); }
            *(bf16x8*)&Out[(size_t)rg * DATT + cg]     = o0;
            *(bf16x8*)&Out[(size_t)rg * DATT + cg + 8] = o1;
        }
        __syncthreads();
    }
}

// ---- K1b: Vb[2048][512] -> Vt[512][2048] bf16, per batch ----
__global__ __launch_bounds__(256) void k_vt(
    const short* __restrict__ Vb, short* __restrict__ Vt)
{
    int b = blockIdx.z;
    int d0 = blockIdx.x * 64;
    int r0 = blockIdx.y * 64;
    const short* Vp = Vb + (size_t)b * S_ * DATT;
    short* Tp = Vt + (size_t)b * DATT * S_;
    __shared__ short tile[64 * 66];
    int t = threadIdx.x;
    #pragma unroll
    for (int i = 0; i < 2; ++i) {
        int slot = t + 256 * i;
        int row = slot >> 3;
        int c8  = (slot & 7) * 8;
        bf16x8 v = *(const bf16x8*)&Vp[(size_t)(r0 + row) * DATT + d0 + c8];
        #pragma unroll
        for (int j = 0; j < 8; ++j) tile[row * 66 + c8 + j] = v[j];
    }
    __syncthreads();
    int dr = t >> 2, rq = (t & 3) * 16;
    bf16x8 o0, o1;
    #pragma unroll
    for (int j = 0; j < 8; ++j) o0[j] = tile[(rq + j) * 66 + dr];
    #pragma unroll
    for (int j = 0; j < 8; ++j) o1[j] = tile[(rq + 8 + j) * 66 + dr];
    *(bf16x8*)&Tp[(size_t)(d0 + dr) * S_ + r0 + rq]     = o0;
    *(bf16x8*)&Tp[(size_t)(d0 + dr) * S_ + r0 + rq + 8] = o1;
}

// ---- K2a: scores -> fp16 raw; BK=64, dbuf prefetch pipeline ----
__global__ __launch_bounds__(256) void k_scores_h(
    const short* __restrict__ Qb, const short* __restrict__ Kb,
    unsigned short* __restrict__ Sraw)
{
    int fid = blockIdx.x + 16 * (blockIdx.y + 16 * blockIdx.z);
    fid = (fid & 7) * 256 + (fid >> 3);
    int bxs = fid & 15;
    int rem = fid >> 4;
    int bys = rem & 15;
    int b   = rem >> 4;

    // LDS: As dbuf 2*16384 + Bs dbuf 2*16384 = 65536 B; Ct aliases front
    __shared__ __align__(16) float smem[16384];
    short* Asb = (short*)smem;               // buf stride 8192 shorts
    short* Bsb = (short*)(smem + 8192);      // buf stride 8192 shorts
    float* Ct  = smem;
    int t = threadIdx.x;
    int l = t & 63, w = t >> 6;
    int wr = (w >> 1) * 64, wc = (w & 1) * 64;
    int fr = l & 15, fk8 = (l >> 4) * 8;
    int xr = (fr & 7) << 3;
    int iBase = bys * 128;
    int jBase = bxs * 128;
    const short* Qp = Qb + (size_t)b * S_ * DATT;
    const short* Kp = Kb + (size_t)b * S_ * DATT;

    f32x4 acc[4][4] = {};
    int srow = w * 8 + (l >> 3);
    int skolsw = (((l & 7) ^ (l >> 3)) * 8);

    // prologue: stage tile 0 into buf 0
    #pragma unroll
    for (int it = 0; it < 4; ++it) {
        int r = it * 32 + srow;
        __builtin_amdgcn_global_load_lds(
            (const __attribute__((address_space(1))) void*)
                &Qp[(size_t)(iBase + r) * DATT + skolsw],
            (__attribute__((address_space(3))) void*)
                &Asb[(it * 32 + w * 8) * 64],
            16, 0, 0);
        __builtin_amdgcn_global_load_lds(
            (const __attribute__((address_space(1))) void*)
                &Kp[(size_t)(jBase + r) * DATT + skolsw],
            (__attribute__((address_space(3))) void*)
                &Bsb[(it * 32 + w * 8) * 64],
            16, 0, 0);
    }
    __syncthreads();

    for (int kt = 0; kt < 8; ++kt) {
        int cur = kt & 1;
        if (kt < 7) {
            int k1 = (kt + 1) * 64;
            short* Ad = Asb + (cur ^ 1) * 8192;
            short* Bd = Bsb + (cur ^ 1) * 8192;
            #pragma unroll
            for (int it = 0; it < 4; ++it) {
                int r = it * 32 + srow;
                __builtin_amdgcn_global_load_lds(
                    (const __attribute__((address_space(1))) void*)
                        &Qp[(size_t)(iBase + r) * DATT + k1 + skolsw],
                    (__attribute__((address_space(3))) void*)
                        &Ad[(it * 32 + w * 8) * 64],
                    16, 0, 0);
                __builtin_amdgcn_global_load_lds(
                    (const __attribute__((address_space(1))) void*)
                        &Kp[(size_t)(jBase + r) * DATT + k1 + skolsw],
                    (__attribute__((address_space(3))) void*)
                        &Bd[(it * 32 + w * 8) * 64],
                    16, 0, 0);
            }
        }
        short* Ac = Asb + cur * 8192;
        short* Bc = Bsb + cur * 8192;
        #pragma unroll
        for (int kk = 0; kk < 64; kk += 32) {
            bf16x8 af[4], bfr[4];
            #pragma unroll
            for (int m = 0; m < 4; ++m)
                af[m] = *(const bf16x8*)&Ac[(wr + m * 16 + fr) * 64 + ((kk + fk8) ^ xr)];
            #pragma unroll
            for (int n = 0; n < 4; ++n)
                bfr[n] = *(const bf16x8*)&Bc[(wc + n * 16 + fr) * 64 + ((kk + fk8) ^ xr)];
            #pragma unroll
            for (int m = 0; m < 4; ++m)
                #pragma unroll
                for (int n = 0; n < 4; ++n)
                    acc[m][n] = __builtin_amdgcn_mfma_f32_16x16x32_bf16(af[m], bfr[n], acc[m][n], 0, 0, 0);
        }
        __syncthreads();
    }

    const float scale = 0.04419417382415922f;   // 1/sqrt(512)
    for (int ch = 0; ch < 4; ++ch) {
        if ((w & 1) == (ch >> 1)) {
            int nb = (ch & 1) * 2;
            #pragma unroll
            for (int n2 = 0; n2 < 2; ++n2)
                #pragma unroll
                for (int m = 0; m < 4; ++m)
                    #pragma unroll
                    for (int q = 0; q < 4; ++q)
                        Ct[(wr + m * 16 + (l >> 4) * 4 + q) * 34 + n2 * 16 + fr]
                            = acc[m][nb + n2][q] * scale;
        }
        __syncthreads();
        {
            int r = t >> 1, seg = (t & 1) * 16;
            size_t base = ((size_t)b * S_ + iBase + r) * S_ + jBase + ch * 32 + seg;
            float vv[16];
            #pragma unroll
            for (int u = 0; u < 4; ++u)
                *(float4*)&vv[4 * u] = *(float4*)&Ct[r * 34 + seg + 4 * u];
            u16x8 h0, h1;
            #pragma unroll
            for (int j = 0; j < 8; ++j) { h0[j] = f2h(vv[j]); h1[j] = f2h(vv[8 + j]); }
            *(u16x8*)&Sraw[base]     = h0;
            *(u16x8*)&Sraw[base + 8] = h1;
        }
        __syncthreads();
    }
}

// ---- K3a: softmax: fp16 raw + mask -> fp32 weights + bf16 Pb (in place) ----
__global__ __launch_bounds__(256) void k_softmax_h(
    unsigned short* __restrict__ SrawPb, const int* __restrict__ mask,
    float* __restrict__ wts)
{
    size_t row = blockIdx.x;
    unsigned short* sp = SrawPb + row * S_;
    const int* mp = mask + row * S_;
    float* wp = wts + row * S_;
    int t = threadIdx.x, l = t & 63, w = t >> 6;

    u16x8 raw = *(const u16x8*)&sp[8 * t];
    int4 m0 = *(const int4*)&mp[8 * t];
    int4 m1 = *(const int4*)&mp[8 * t + 4];
    float v[8];
    v[0] = (m0.x == 0) ? -1e-9f : h2f(raw[0]);
    v[1] = (m0.y == 0) ? -1e-9f : h2f(raw[1]);
    v[2] = (m0.z == 0) ? -1e-9f : h2f(raw[2]);
    v[3] = (m0.w == 0) ? -1e-9f : h2f(raw[3]);
    v[4] = (m1.x == 0) ? -1e-9f : h2f(raw[4]);
    v[5] = (m1.y == 0) ? -1e-9f : h2f(raw[5]);
    v[6] = (m1.z == 0) ? -1e-9f : h2f(raw[6]);
    v[7] = (m1.w == 0) ? -1e-9f : h2f(raw[7]);

    float mx = v[0];
    #pragma unroll
    for (int j = 1; j < 8; ++j) mx = fmaxf(mx, v[j]);
    for (int off = 32; off; off >>= 1) mx = fmaxf(mx, __shfl_xor(mx, off));
    __shared__ float red[8];
    if (l == 0) red[w] = mx;
    __syncthreads();
    mx = fmaxf(fmaxf(red[0], red[1]), fmaxf(red[2], red[3]));
    float sum = 0.f;
    #pragma unroll
    for (int j = 0; j < 8; ++j) { v[j] = expf(v[j] - mx); sum += v[j]; }
    for (int off = 32; off; off >>= 1) sum += __shfl_xor(sum, off);
    if (l == 0) red[4 + w] = sum;
    __syncthreads();
    sum = red[4] + red[5] + red[6] + red[7];
    float inv = 1.0f / sum;
    #pragma unroll
    for (int j = 0; j < 8; ++j) v[j] *= inv;

    *(float4*)&wp[8 * t]     = make_float4(v[0], v[1], v[2], v[3]);
    *(float4*)&wp[8 * t + 4] = make_float4(v[4], v[5], v[6], v[7]);
    bf16x8 pb8;
    #pragma unroll
    for (int j = 0; j < 8; ++j) pb8[j] = f2bf(v[j]);
    *(bf16x8*)&sp[8 * t] = pb8;   // Pb overwrites Sraw in place
}

// ---- K4a: context = Pb(bf16) @ Vt^T; BK=64, dbuf prefetch pipeline ----
__global__ __launch_bounds__(256) void k_ctx_bf16(
    const short* __restrict__ Pb, const short* __restrict__ Vt,
    float* __restrict__ ctx)
{
    int fid = blockIdx.x + 4 * (blockIdx.y + 16 * blockIdx.z);
    fid = (fid & 7) * 64 + (fid >> 3);
    int bxs = fid & 3;
    int rem = fid >> 2;
    int bys = rem & 15;
    int b   = rem >> 4;

    __shared__ __align__(16) float smem[16384];
    short* Asb = (short*)smem;
    short* Bsb = (short*)(smem + 8192);
    float* Ct  = smem;
    int t = threadIdx.x;
    int l = t & 63, w = t >> 6;
    int wr = (w >> 1) * 64, wc = (w & 1) * 64;
    int fr = l & 15, fk8 = (l >> 4) * 8;
    int xr = (fr & 7) << 3;
    int iBase = bys * 128;
    int nBase = bxs * 128;
    const short* Ap = Pb + (size_t)b * S_ * S_;
    const short* Bp = Vt + (size_t)b * DATT * S_;

    f32x4 acc[4][4] = {};
    int srow = w * 8 + (l >> 3);
    int skolsw = (((l & 7) ^ (l >> 3)) * 8);

    #pragma unroll
    for (int it = 0; it < 4; ++it) {
        int r = it * 32 + srow;
        __builtin_amdgcn_global_load_lds(
            (const __attribute__((address_space(1))) void*)
                &Ap[(size_t)(iBase + r) * S_ + skolsw],
            (__attribute__((address_space(3))) void*)
                &Asb[(it * 32 + w * 8) * 64],
            16, 0, 0);
        __builtin_amdgcn_global_load_lds(
            (const __attribute__((address_space(1))) void*)
                &Bp[(size_t)(nBase + r) * S_ + skolsw],
            (__attribute__((address_space(3))) void*)
                &Bsb[(it * 32 + w * 8) * 64],
            16, 0, 0);
    }
    __syncthreads();

    for (int kt = 0; kt < 32; ++kt) {
        int cur = kt & 1;
        if (kt < 31) {
            int k1 = (kt + 1) * 64;
            short* Ad = Asb + (cur ^ 1) * 8192;
            short* Bd = Bsb + (cur ^ 1) * 8192;
            #pragma unroll
            for (int it = 0; it < 4; ++it) {
                int r = it * 32 + srow;
                __builtin_amdgcn_global_load_lds(
                    (const __attribute__((address_space(1))) void*)
                        &Ap[(size_t)(iBase + r) * S_ + k1 + skolsw],
                    (__attribute__((address_space(3))) void*)
                        &Ad[(it * 32 + w * 8) * 64],
                    16, 0, 0);
                __builtin_amdgcn_global_load_lds(
                    (const __attribute__((address_space(1))) void*)
                        &Bp[(size_t)(nBase + r) * S_ + k1 + skolsw],
                    (__attribute__((address_space(3))) void*)
                        &Bd[(it * 32 + w * 8) * 64],
                    16, 0, 0);
            }
        }
        short* Ac = Asb + cur * 8192;
        short* Bc = Bsb + cur * 8192;
        #pragma unroll
        for (int kk = 0; kk < 64; kk += 32) {
            bf16x8 af[4], bfr[4];
            #pragma unroll
            for (int m = 0; m < 4; ++m)
                af[m] = *(const bf16x8*)&Ac[(wr + m * 16 + fr) * 64 + ((kk + fk8) ^ xr)];
            #pragma unroll
            for (int n = 0; n < 4; ++n)
                bfr[n] = *(const bf16x8*)&Bc[(wc + n * 16 + fr) * 64 + ((kk + fk8) ^ xr)];
            #pragma unroll
            for (int m = 0; m < 4; ++m)
                #pragma unroll
                for (int n = 0; n < 4; ++n)
                    acc[m][n] = __builtin_amdgcn_mfma_f32_16x16x32_bf16(af[m], bfr[n], acc[m][n], 0, 0, 0);
        }
        __syncthreads();
    }

    for (int ch = 0; ch < 4; ++ch) {
        if ((w & 1) == (ch >> 1)) {
            int nb = (ch & 1) * 2;
            #pragma unroll
            for (int n2 = 0; n2 < 2; ++n2)
                #pragma unroll
                for (int m = 0; m < 4; ++m)
                    #pragma unroll
                    for (int q = 0; q < 4; ++q)
                        Ct[(wr + m * 16 + (l >> 4) * 4 + q) * 34 + n2 * 16 + fr]
                            = acc[m][nb + n2][q];
        }
        __syncthreads();
        {
            int r = t >> 1, seg = (t & 1) * 16;
            int gi = iBase + r;
            size_t base = ((size_t)b * S_ + gi) * DATT + nBase + ch * 32 + seg;
            #pragma unroll
            for (int u = 0; u < 4; ++u) {
                float4 vv = *(float4*)&Ct[r * 34 + seg + 4 * u];
                *(float4*)&ctx[base + 4 * u] = vv;
            }
        }
        __syncthreads();
    }
}

// ================= fallback path (small ws), BK=32 legacy =========
__global__ __launch_bounds__(256) void k_scores_f32(
    const short* __restrict__ Qb, const short* __restrict__ Kb,
    const int* __restrict__ mask, float* __restrict__ wOut)
{
    __shared__ __align__(16) float smem[4352];
    short* As = (short*)smem;
    short* Bs = (short*)(smem + 2048);
    float* Ct = smem;
    int t = threadIdx.x;
    int l = t & 63, w = t >> 6;
    int wr = (w >> 1) * 64, wc = (w & 1) * 64;
    int fr = l & 15, fk = (l >> 4) * 8;
    int b = blockIdx.z;
    int iBase = blockIdx.y * 128;
    int jBase = blockIdx.x * 128;
    const short* Qp = Qb + (size_t)b * S_ * DATT;
    const short* Kp = Kb + (size_t)b * S_ * DATT;

    f32x4 acc[4][4] = {};
    int srow = w * 16 + (l >> 2);
    int skol = (l & 3) * 8;

    for (int k0 = 0; k0 < DATT; k0 += 32) {
        #pragma unroll
        for (int it = 0; it < 2; ++it) {
            int r = it * 64 + srow;
            __builtin_amdgcn_global_load_lds(
                (const __attribute__((address_space(1))) void*)
                    &Qp[(size_t)(iBase + r) * DATT + k0 + skol],
                (__attribute__((address_space(3))) void*)
                    &As[(it * 64 + w * 16) * 32],
                16, 0, 0);
            __builtin_amdgcn_global_load_lds(
                (const __attribute__((address_space(1))) void*)
                    &Kp[(size_t)(jBase + r) * DATT + k0 + skol],
                (__attribute__((address_space(3))) void*)
                    &Bs[(it * 64 + w * 16) * 32],
                16, 0, 0);
        }
        __syncthreads();
        bf16x8 af[4], bfr[4];
        #pragma unroll
        for (int m = 0; m < 4; ++m)
            af[m] = *(const bf16x8*)&As[(wr + m * 16 + fr) * 32 + fk];
        #pragma unroll
        for (int n = 0; n < 4; ++n)
            bfr[n] = *(const bf16x8*)&Bs[(wc + n * 16 + fr) * 32 + fk];
        #pragma unroll
        for (int m = 0; m < 4; ++m)
            #pragma unroll
            for (int n = 0; n < 4; ++n)
                acc[m][n] = __builtin_amdgcn_mfma_f32_16x16x32_bf16(af[m], bfr[n], acc[m][n], 0, 0, 0);
        __syncthreads();
    }

    const float scale = 0.04419417382415922f;
    for (int ch = 0; ch < 4; ++ch) {
        if ((w & 1) == (ch >> 1)) {
            int nb = (ch & 1) * 2;
            #pragma unroll
            for (int n2 = 0; n2 < 2; ++n2)
                #pragma unroll
                for (int m = 0; m < 4; ++m)
                    #pragma unroll
                    for (int q = 0; q < 4; ++q)
                        Ct[(wr + m * 16 + (l >> 4) * 4 + q) * 34 + n2 * 16 + fr]
                            = acc[m][nb + n2][q] * scale;
        }
        __syncthreads();
        {
            int r = t >> 1, seg = (t & 1) * 16;
            size_t base = ((size_t)b * S_ + iBase + r) * S_ + jBase + ch * 32 + seg;
            #pragma unroll
            for (int u = 0; u < 4; ++u) {
                float4 vv = *(float4*)&Ct[r * 34 + seg + 4 * u];
                int4  mm = *(const int4*)&mask[base + 4 * u];
                vv.x = (mm.x == 0) ? -1e-9f : vv.x;
                vv.y = (mm.y == 0) ? -1e-9f : vv.y;
                vv.z = (mm.z == 0) ? -1e-9f : vv.z;
                vv.w = (mm.w == 0) ? -1e-9f : vv.w;
                *(float4*)&wOut[base + 4 * u] = vv;
            }
        }
        __syncthreads();
    }
}

__global__ __launch_bounds__(256) void k_softmax_f32(float* __restrict__ wts) {
    size_t row = blockIdx.x;
    float* p = wts + row * S_;
    int t = threadIdx.x, l = t & 63, w = t >> 6;
    float v[8];
    *(float4*)&v[0] = ((const float4*)p)[t];
    *(float4*)&v[4] = ((const float4*)p)[t + 256];
    float mx = v[0];
    #pragma unroll
    for (int j = 1; j < 8; ++j) mx = fmaxf(mx, v[j]);
    for (int off = 32; off; off >>= 1) mx = fmaxf(mx, __shfl_xor(mx, off));
    __shared__ float red[8];
    if (l == 0) red[w] = mx;
    __syncthreads();
    mx = fmaxf(fmaxf(red[0], red[1]), fmaxf(red[2], red[3]));
    float sum = 0.f;
    #pragma unroll
    for (int j = 0; j < 8; ++j) { v[j] = expf(v[j] - mx); sum += v[j]; }
    for (int off = 32; off; off >>= 1) sum += __shfl_xor(sum, off);
    if (l == 0) red[4 + w] = sum;
    __syncthreads();
    sum = red[4] + red[5] + red[6] + red[7];
    float inv = 1.0f / sum;
    #pragma unroll
    for (int j = 0; j < 8; ++j) v[j] *= inv;
    ((float4*)p)[t]       = *(float4*)&v[0];
    ((float4*)p)[t + 256] = *(float4*)&v[4];
}

__global__ __launch_bounds__(256) void k_ctx_f32(
    const float* __restrict__ wts, const short* __restrict__ Vt,
    float* __restrict__ ctx)
{
    __shared__ short As[128 * 40];
    __shared__ short Bs[128 * 32];
    int t = threadIdx.x;
    int l = t & 63, w = t >> 6;
    int wr = (w >> 1) * 64, wc = (w & 1) * 64;
    int fr = l & 15, fk = (l >> 4) * 8;
    int b = blockIdx.z;
    int iBase = blockIdx.y * 128;
    int nBase = blockIdx.x * 128;
    const float* Wp = wts + (size_t)b * S_ * S_;
    const short* Bp = Vt + (size_t)b * DATT * S_;

    f32x4 acc[4][4] = {};
    int trA = t >> 3, tcA = (t & 7) * 4;
    int srow = w * 16 + (l >> 2), skol = (l & 3) * 8;

    for (int k0 = 0; k0 < S_; k0 += 32) {
        #pragma unroll
        for (int it = 0; it < 2; ++it) {
            int r = it * 64 + srow;
            __builtin_amdgcn_global_load_lds(
                (const __attribute__((address_space(1))) void*)
                    &Bp[(size_t)(nBase + r) * S_ + k0 + skol],
                (__attribute__((address_space(3))) void*)
                    &Bs[(it * 64 + w * 16) * 32],
                16, 0, 0);
        }
        #pragma unroll
        for (int ii = 0; ii < 4; ++ii) {
            int r = trA + 32 * ii;
            float4 v = *(const float4*)&Wp[(size_t)(iBase + r) * S_ + k0 + tcA];
            short4 s4 = make_short4(f2bf(v.x), f2bf(v.y), f2bf(v.z), f2bf(v.w));
            *(short4*)&As[r * 40 + tcA] = s4;
        }
        __syncthreads();
        bf16x8 af[4], bfr[4];
        #pragma unroll
        for (int m = 0; m < 4; ++m)
            af[m] = *(const bf16x8*)&As[(wr + m * 16 + fr) * 40 + fk];
        #pragma unroll
        for (int n = 0; n < 4; ++n)
            bfr[n] = *(const bf16x8*)&Bs[(wc + n * 16 + fr) * 32 + fk];
        #pragma unroll
        for (int m = 0; m < 4; ++m)
            #pragma unroll
            for (int n = 0; n < 4; ++n)
                acc[m][n] = __builtin_amdgcn_mfma_f32_16x16x32_bf16(af[m], bfr[n], acc[m][n], 0, 0, 0);
        __syncthreads();
    }

    for (int m = 0; m < 4; ++m) {
        for (int q = 0; q < 4; ++q) {
            int i = iBase + wr + m * 16 + (l >> 4) * 4 + q;
            for (int n = 0; n < 4; ++n) {
                int d = nBase + wc + n * 16 + fr;
                ctx[((size_t)b * S_ + i) * DATT + d] = acc[m][n][q];
            }
        }
    }
}

extern "C" void kernel_launch(void* const* d_in, const int* in_sizes, int n_in,
                              void* d_out, int out_size, void* d_ws, size_t ws_size,
                              hipStream_t stream) {
    const float* query = (const float*)d_in[0];
    const float* key   = (const float*)d_in[1];
    const float* value = (const float*)d_in[2];
    const int*   mask  = (const int*)d_in[3];
    const float* Wq = (const float*)d_in[4];
    const float* bq = (const float*)d_in[5];
    const float* Wk = (const float*)d_in[6];
    const float* bk = (const float*)d_in[7];
    const float* Wv = (const float*)d_in[8];
    const float* bv = (const float*)d_in[9];

    float* ctx = (float*)d_out;                    // B*S*DATT fp32
    float* wts = ctx + (size_t)B_ * S_ * DATT;     // B*S*S fp32

    char* ws = (char*)d_ws;
    const size_t SZ_QKV = (size_t)B_ * S_ * DATT * 2;      // 16.78 MB
    const size_t SZ_WT  = (size_t)DATT * DIN * 2;          // 512 KB
    const size_t SZ_TAB = (size_t)S_ * 256 * 4;            // 2 MB
    short* Qb   = (short*)(ws);
    short* Kb   = (short*)(ws + SZ_QKV);
    short* Vt   = (short*)(ws + 2 * SZ_QKV);
    short* WtQ  = (short*)(ws + 3 * SZ_QKV);
    float* cosT = (float*)(ws + 3 * SZ_QKV + 3 * SZ_WT);
    float* sinT = (float*)(ws + 3 * SZ_QKV + 3 * SZ_WT + SZ_TAB);
    char*  big  = ws + 3 * SZ_QKV + 3 * SZ_WT + 2 * SZ_TAB;
    short* Vb   = (short*)big;                 // dead after k_vt
    unsigned short* Sraw = (unsigned short*)big;  // fp16 raw -> bf16 Pb in place
    const size_t needA = 3 * SZ_QKV + 3 * SZ_WT + 2 * SZ_TAB
                       + (size_t)B_ * S_ * S_ * 2;          // ~123.2 MB
    int useH = ws_size >= needA ? 1 : 0;

    short* WtK = WtQ + (size_t)DATT * DIN;
    short* WtV = WtK + (size_t)DATT * DIN;

    k_prep<<<dim3(1216), 256, 0, stream>>>(cosT, sinT, Wq, Wk, Wv, WtQ, WtK, WtV);
    k_proj3<<<dim3(4, 128, 3), 256, 0, stream>>>(query, key, value, WtQ,
                                                 bq, bk, bv, Qb, Kb, Vb,
                                                 cosT, sinT);
    k_vt<<<dim3(8, 32, 8), 256, 0, stream>>>(Vb, Vt);
    if (useH) {
        k_scores_h<<<dim3(16, 16, 8), 256, 0, stream>>>(Qb, Kb, Sraw);
        k_softmax_h<<<dim3(B_ * S_), 256, 0, stream>>>(Sraw, mask, wts);
        k_ctx_bf16<<<dim3(4, 16, 8), 256, 0, stream>>>((short*)Sraw, Vt, ctx);
    } else {
        k_scores_f32<<<dim3(16, 16, 8), 256, 0, stream>>>(Qb, Kb, mask, wts);
        k_softmax_f32<<<dim3(B_ * S_), 256, 0, stream>>>(wts);
        k_ctx_f32<<<dim3(4, 16, 8), 256, 0, stream>>>(wts, Vt, ctx);
    }
}